// Round 1
// baseline (927.433 us; speedup 1.0000x reference)
//
#include <hip/hip_runtime.h>

#define NN 100000
#define NE 1600000
#define NB_SCAN 98  // ceil(NN/1024)

// ---------------- CSR build ----------------

__global__ void zero_int_kernel(int* __restrict__ p, int n) {
    int i = blockIdx.x * blockDim.x + threadIdx.x;
    if (i < n) p[i] = 0;
}

__global__ void count_kernel(const int* __restrict__ dst, int* __restrict__ count) {
    int e = blockIdx.x * blockDim.x + threadIdx.x;
    if (e < NE) atomicAdd(&count[dst[e]], 1);
}

// per-1024-chunk sums
__global__ __launch_bounds__(256) void block_sum_kernel(const int* __restrict__ count,
                                                        int* __restrict__ bsum) {
    __shared__ int sdata[256];
    int t = threadIdx.x;
    int base = blockIdx.x * 1024;
    int s = 0;
    for (int i = t; i < 1024; i += 256) {
        int idx = base + i;
        s += (idx < NN) ? count[idx] : 0;
    }
    sdata[t] = s;
    __syncthreads();
    for (int off = 128; off > 0; off >>= 1) {
        if (t < off) sdata[t] += sdata[t + off];
        __syncthreads();
    }
    if (t == 0) bsum[blockIdx.x] = sdata[0];
}

// serial exclusive scan of the 98 block sums (tiny)
__global__ void scan_bsum_kernel(int* __restrict__ bsum, int nb) {
    if (blockIdx.x == 0 && threadIdx.x == 0) {
        int run = 0;
        for (int i = 0; i < nb; ++i) {
            int v = bsum[i];
            bsum[i] = run;
            run += v;
        }
    }
}

// per-block exclusive scan -> row_ptr, and init cursor
__global__ __launch_bounds__(1024) void scan_block_kernel(const int* __restrict__ count,
                                                          const int* __restrict__ bsum,
                                                          int* __restrict__ row_ptr,
                                                          int* __restrict__ cursor) {
    __shared__ int sdata[1024];
    int t = threadIdx.x;
    int idx = blockIdx.x * 1024 + t;
    int v = (idx < NN) ? count[idx] : 0;
    sdata[t] = v;
    __syncthreads();
    for (int off = 1; off < 1024; off <<= 1) {
        int add = (t >= off) ? sdata[t - off] : 0;
        __syncthreads();
        sdata[t] += add;
        __syncthreads();
    }
    if (idx < NN) {
        int excl = sdata[t] - v + bsum[blockIdx.x];
        row_ptr[idx] = excl;
        cursor[idx]  = excl;
        if (idx == NN - 1) row_ptr[NN] = excl + v;  // == NE
    }
}

__global__ void fill_adj_kernel(const int* __restrict__ src, const int* __restrict__ dst,
                                int* __restrict__ cursor, int* __restrict__ adj) {
    int e = blockIdx.x * blockDim.x + threadIdx.x;
    if (e >= NE) return;
    int d = dst[e];
    int pos = atomicAdd(&cursor[d], 1);
    adj[pos] = src[e];
}

// ---------------- pull aggregation (mean over in-neighbors) ----------------

// one wave per dst node; lane i owns features [2i, 2i+1]  (F = 128)
__global__ __launch_bounds__(256) void pull_mean128_kernel(const float* __restrict__ xin,
                                                           const int* __restrict__ row_ptr,
                                                           const int* __restrict__ adj,
                                                           float* __restrict__ aggout) {
    int node = blockIdx.x * 4 + (threadIdx.x >> 6);
    if (node >= NN) return;
    int lane = threadIdx.x & 63;
    int beg = row_ptr[node], end = row_ptr[node + 1];
    float ax = 0.f, ay = 0.f;
    for (int p = beg; p < end; ++p) {
        int s = adj[p];
        const float2 v = ((const float2*)(xin + (size_t)s * 128))[lane];
        ax += v.x;
        ay += v.y;
    }
    float inv = 1.0f / (float)(end > beg ? (end - beg) : 1);
    float2 r;
    r.x = ax * inv;
    r.y = ay * inv;
    ((float2*)(aggout + (size_t)node * 128))[lane] = r;
}

// one wave per dst node; lane i owns feature i  (F = 64)
__global__ __launch_bounds__(256) void pull_mean64_kernel(const float* __restrict__ zin,
                                                          const int* __restrict__ row_ptr,
                                                          const int* __restrict__ adj,
                                                          float* __restrict__ aggout) {
    int node = blockIdx.x * 4 + (threadIdx.x >> 6);
    if (node >= NN) return;
    int lane = threadIdx.x & 63;
    int beg = row_ptr[node], end = row_ptr[node + 1];
    float acc = 0.f;
    for (int p = beg; p < end; ++p) {
        int s = adj[p];
        acc += zin[(size_t)s * 64 + lane];
    }
    float inv = 1.0f / (float)(end > beg ? (end - beg) : 1);
    aggout[(size_t)node * 64 + lane] = acc * inv;
}

// ---------------- fused SAGE layer (H=128): out = act(agg@Wl + xin@Wr + b) ----------------
// BM=64 rows/block, full H=128, K=256 (agg cols then xin cols), BK=32, 256 threads.

template <bool RELU>
__global__ __launch_bounds__(256) void sage_layer128_kernel(
    const float* __restrict__ agg, const float* __restrict__ xin,
    const float* __restrict__ Wl, const float* __restrict__ Wr,
    const float* __restrict__ bias, float* __restrict__ out, int n_rows) {
    __shared__ float As[64][40];   // pad 40 -> float4-aligned stores, spread banks
    __shared__ float Bs[32][128];

    const int t    = threadIdx.x;
    const int row0 = blockIdx.x * 64;
    const int h0   = (t & 15) * 8;   // 16 groups x 8 feats = 128
    const int n0   = (t >> 4) * 4;   // 16 groups x 4 rows  = 64

    float acc[4][8];
#pragma unroll
    for (int i = 0; i < 4; ++i)
#pragma unroll
        for (int j = 0; j < 8; ++j) acc[i][j] = 0.f;

    const int an = t >> 2;        // 0..63
    const int ak = (t & 3) * 8;   // 0..24
    const int bk = t >> 3;        // 0..31
    const int bh = (t & 7) * 16;  // 0..112

    for (int kt = 0; kt < 8; ++kt) {
        const int k0 = kt * 32;
        const float* Asrc = (k0 < 128) ? agg : xin;
        const float* Bsrc = (k0 < 128) ? Wl : Wr;
        const int ka = (k0 < 128) ? k0 : (k0 - 128);

        // A tile: 64x32
        {
            int r = row0 + an;
            float4 v0, v1;
            if (r < n_rows) {
                const float4* p = (const float4*)(Asrc + (size_t)r * 128 + ka + ak);
                v0 = p[0];
                v1 = p[1];
            } else {
                v0 = make_float4(0.f, 0.f, 0.f, 0.f);
                v1 = v0;
            }
            float4* q = (float4*)(&As[an][ak]);
            q[0] = v0;
            q[1] = v1;
        }
        // B tile: 32x128
        {
            const float4* p = (const float4*)(Bsrc + (size_t)(ka + bk) * 128 + bh);
            float4* q = (float4*)(&Bs[bk][bh]);
            q[0] = p[0];
            q[1] = p[1];
            q[2] = p[2];
            q[3] = p[3];
        }
        __syncthreads();

#pragma unroll
        for (int kk = 0; kk < 32; ++kk) {
            float a0 = As[n0 + 0][kk];
            float a1 = As[n0 + 1][kk];
            float a2 = As[n0 + 2][kk];
            float a3 = As[n0 + 3][kk];
            float4 bv0 = *(const float4*)(&Bs[kk][h0]);
            float4 bv1 = *(const float4*)(&Bs[kk][h0 + 4]);
            float bvals[8] = {bv0.x, bv0.y, bv0.z, bv0.w, bv1.x, bv1.y, bv1.z, bv1.w};
#pragma unroll
            for (int j = 0; j < 8; ++j) {
                acc[0][j] += a0 * bvals[j];
                acc[1][j] += a1 * bvals[j];
                acc[2][j] += a2 * bvals[j];
                acc[3][j] += a3 * bvals[j];
            }
        }
        __syncthreads();
    }

    float bv[8];
#pragma unroll
    for (int j = 0; j < 8; ++j) bv[j] = bias[h0 + j];
#pragma unroll
    for (int i = 0; i < 4; ++i) {
        int r = row0 + n0 + i;
        if (r < n_rows) {
            float vals[8];
#pragma unroll
            for (int j = 0; j < 8; ++j) {
                float v = acc[i][j] + bv[j];
                if (RELU) v = fmaxf(v, 0.f);
                vals[j] = v;
            }
            float4* q = (float4*)(out + (size_t)r * 128 + h0);
            q[0] = *(float4*)(&vals[0]);
            q[1] = *(float4*)(&vals[4]);
        }
    }
}

// ---------------- C[N,64] = A[N,128] @ W[128,64] (+ addin) (+ bias) ----------------

template <bool HAS_ADD, bool HAS_BIAS>
__global__ __launch_bounds__(256) void matmul64_kernel(
    const float* __restrict__ A, const float* __restrict__ W,
    const float* __restrict__ addin, const float* __restrict__ bias,
    float* __restrict__ out, int n_rows) {
    __shared__ float As[64][40];
    __shared__ float Bs[32][64];

    const int t    = threadIdx.x;
    const int row0 = blockIdx.x * 64;
    const int h0   = (t & 15) * 4;  // 16 x 4 = 64
    const int n0   = (t >> 4) * 4;  // 16 x 4 = 64

    float acc[4][4];
#pragma unroll
    for (int i = 0; i < 4; ++i)
#pragma unroll
        for (int j = 0; j < 4; ++j) acc[i][j] = 0.f;

    const int an = t >> 2;        // 0..63
    const int ak = (t & 3) * 8;   // 0..24
    const int bk = t >> 3;        // 0..31
    const int bh = (t & 7) * 8;   // 0..56

    for (int kt = 0; kt < 4; ++kt) {
        const int k0 = kt * 32;
        {
            int r = row0 + an;
            float4 v0, v1;
            if (r < n_rows) {
                const float4* p = (const float4*)(A + (size_t)r * 128 + k0 + ak);
                v0 = p[0];
                v1 = p[1];
            } else {
                v0 = make_float4(0.f, 0.f, 0.f, 0.f);
                v1 = v0;
            }
            float4* q = (float4*)(&As[an][ak]);
            q[0] = v0;
            q[1] = v1;
        }
        {
            const float4* p = (const float4*)(W + (size_t)(k0 + bk) * 64 + bh);
            float4* q = (float4*)(&Bs[bk][bh]);
            q[0] = p[0];
            q[1] = p[1];
        }
        __syncthreads();

#pragma unroll
        for (int kk = 0; kk < 32; ++kk) {
            float a0 = As[n0 + 0][kk];
            float a1 = As[n0 + 1][kk];
            float a2 = As[n0 + 2][kk];
            float a3 = As[n0 + 3][kk];
            float4 bv = *(const float4*)(&Bs[kk][h0]);
            float bvals[4] = {bv.x, bv.y, bv.z, bv.w};
#pragma unroll
            for (int j = 0; j < 4; ++j) {
                acc[0][j] += a0 * bvals[j];
                acc[1][j] += a1 * bvals[j];
                acc[2][j] += a2 * bvals[j];
                acc[3][j] += a3 * bvals[j];
            }
        }
        __syncthreads();
    }

#pragma unroll
    for (int i = 0; i < 4; ++i) {
        int r = row0 + n0 + i;
        if (r < n_rows) {
            float vals[4];
#pragma unroll
            for (int j = 0; j < 4; ++j) {
                float v = acc[i][j];
                if (HAS_ADD) v += addin[(size_t)r * 64 + h0 + j];
                if (HAS_BIAS) v += bias[h0 + j];
                vals[j] = v;
            }
            float4* q = (float4*)(out + (size_t)r * 64 + h0);
            q[0] = *(float4*)(&vals[0]);
        }
    }
}

// ---------------- launcher ----------------

extern "C" void kernel_launch(void* const* d_in, const int* in_sizes, int n_in,
                              void* d_out, int out_size, void* d_ws, size_t ws_size,
                              hipStream_t stream) {
    (void)in_sizes; (void)n_in; (void)out_size; (void)ws_size;

    const float* x   = (const float*)d_in[0];
    const int* eidx  = (const int*)d_in[1];
    const int* src   = eidx;
    const int* dst   = eidx + NE;
    const float* W1l = (const float*)d_in[2];
    const float* W1r = (const float*)d_in[3];
    const float* b1  = (const float*)d_in[4];
    const float* W2l = (const float*)d_in[5];
    const float* W2r = (const float*)d_in[6];
    const float* b2  = (const float*)d_in[7];
    const float* W3l = (const float*)d_in[8];
    const float* W3r = (const float*)d_in[9];
    const float* b3  = (const float*)d_in[10];
    float* out = (float*)d_out;

    // workspace carve (256B aligned)
    size_t off = 0;
    auto carve = [&](size_t bytes) -> void* {
        void* p = (char*)d_ws + off;
        off += (bytes + 255) & ~(size_t)255;
        return p;
    };
    int* count   = (int*)carve((size_t)NN * 4);
    int* row_ptr = (int*)carve((size_t)(NN + 1) * 4);
    int* cursor  = (int*)carve((size_t)NN * 4);
    int* bsum    = (int*)carve((size_t)NB_SCAN * 4);
    int* adj     = (int*)carve((size_t)NE * 4);
    float* agg   = (float*)carve((size_t)NN * 128 * 4);
    float* h1    = (float*)carve((size_t)NN * 128 * 4);
    float* h2    = (float*)carve((size_t)NN * 128 * 4);
    float* z     = h1;   // reused after layer 2 (N*64 <= N*128)
    float* agg3  = agg;  // reused (N*64)

    const int egrid = (NE + 255) / 256;
    const int ngrid = (NN + 255) / 256;
    const int mgrid = (NN + 63) / 64;      // 1563
    const int pgrid = (NN + 3) / 4;        // 25000

    // --- CSR build ---
    zero_int_kernel<<<ngrid, 256, 0, stream>>>(count, NN);
    count_kernel<<<egrid, 256, 0, stream>>>(dst, count);
    block_sum_kernel<<<NB_SCAN, 256, 0, stream>>>(count, bsum);
    scan_bsum_kernel<<<1, 64, 0, stream>>>(bsum, NB_SCAN);
    scan_block_kernel<<<NB_SCAN, 1024, 0, stream>>>(count, bsum, row_ptr, cursor);
    fill_adj_kernel<<<egrid, 256, 0, stream>>>(src, dst, cursor, adj);

    // --- layer 1 ---
    pull_mean128_kernel<<<pgrid, 256, 0, stream>>>(x, row_ptr, adj, agg);
    sage_layer128_kernel<true><<<mgrid, 256, 0, stream>>>(agg, x, W1l, W1r, b1, h1, NN);

    // --- layer 2 ---
    pull_mean128_kernel<<<pgrid, 256, 0, stream>>>(h1, row_ptr, adj, agg);
    sage_layer128_kernel<true><<<mgrid, 256, 0, stream>>>(agg, h1, W2l, W2r, b2, h2, NN);

    // --- layer 3: aggregate after projecting (mean is linear): z = h2 @ W3l ---
    matmul64_kernel<false, false><<<mgrid, 256, 0, stream>>>(h2, W3l, nullptr, nullptr, z, NN);
    pull_mean64_kernel<<<pgrid, 256, 0, stream>>>(z, row_ptr, adj, agg3);
    matmul64_kernel<true, true><<<mgrid, 256, 0, stream>>>(h2, W3r, agg3, b3, out, NN);
}

// Round 2
// 683.016 us; speedup vs baseline: 1.3578x; 1.3578x over previous
//
#include <hip/hip_runtime.h>

#define NN 100000
#define NE 1600000
#define NB_SCAN 98  // ceil(NN/1024)

// ---------------- bf16 helpers (stored as ushort/uint, math in fp32) ----------------

__device__ __forceinline__ unsigned short f2bf(float f) {
    unsigned int u = __float_as_uint(f);
    unsigned int r = u + 0x7fffu + ((u >> 16) & 1u);  // RNE
    return (unsigned short)(r >> 16);
}
__device__ __forceinline__ float bf2f(unsigned short h) {
    return __uint_as_float(((unsigned int)h) << 16);
}
__device__ __forceinline__ float bflo(unsigned int u) { return __uint_as_float(u << 16); }
__device__ __forceinline__ float bfhi(unsigned int u) { return __uint_as_float(u & 0xffff0000u); }
__device__ __forceinline__ unsigned int packbf(float lo, float hi) {
    return ((unsigned int)f2bf(hi) << 16) | (unsigned int)f2bf(lo);
}

// ---------------- CSR build ----------------

__global__ void zero_int_kernel(int* __restrict__ p, int n) {
    int i = blockIdx.x * blockDim.x + threadIdx.x;
    if (i < n) p[i] = 0;
}

__global__ void count_kernel(const int* __restrict__ dst, int* __restrict__ count) {
    int e = blockIdx.x * blockDim.x + threadIdx.x;
    if (e < NE) atomicAdd(&count[dst[e]], 1);
}

__global__ __launch_bounds__(256) void block_sum_kernel(const int* __restrict__ count,
                                                        int* __restrict__ bsum) {
    __shared__ int sdata[256];
    int t = threadIdx.x;
    int base = blockIdx.x * 1024;
    int s = 0;
    for (int i = t; i < 1024; i += 256) {
        int idx = base + i;
        s += (idx < NN) ? count[idx] : 0;
    }
    sdata[t] = s;
    __syncthreads();
    for (int off = 128; off > 0; off >>= 1) {
        if (t < off) sdata[t] += sdata[t + off];
        __syncthreads();
    }
    if (t == 0) bsum[blockIdx.x] = sdata[0];
}

__global__ void scan_bsum_kernel(int* __restrict__ bsum, int nb) {
    if (blockIdx.x == 0 && threadIdx.x == 0) {
        int run = 0;
        for (int i = 0; i < nb; ++i) {
            int v = bsum[i];
            bsum[i] = run;
            run += v;
        }
    }
}

__global__ __launch_bounds__(1024) void scan_block_kernel(const int* __restrict__ count,
                                                          const int* __restrict__ bsum,
                                                          int* __restrict__ row_ptr,
                                                          int* __restrict__ cursor) {
    __shared__ int sdata[1024];
    int t = threadIdx.x;
    int idx = blockIdx.x * 1024 + t;
    int v = (idx < NN) ? count[idx] : 0;
    sdata[t] = v;
    __syncthreads();
    for (int off = 1; off < 1024; off <<= 1) {
        int add = (t >= off) ? sdata[t - off] : 0;
        __syncthreads();
        sdata[t] += add;
        __syncthreads();
    }
    if (idx < NN) {
        int excl = sdata[t] - v + bsum[blockIdx.x];
        row_ptr[idx] = excl;
        cursor[idx]  = excl;
        if (idx == NN - 1) row_ptr[NN] = excl + v;
    }
}

__global__ void fill_adj_kernel(const int* __restrict__ src, const int* __restrict__ dst,
                                int* __restrict__ cursor, int* __restrict__ adj) {
    int e = blockIdx.x * blockDim.x + threadIdx.x;
    if (e >= NE) return;
    int d = dst[e];
    int pos = atomicAdd(&cursor[d], 1);
    adj[pos] = src[e];
}

// ---------------- fp32 -> bf16 conversion (8 elems / thread) ----------------

__global__ __launch_bounds__(256) void f32_to_bf16_kernel(const float* __restrict__ in,
                                                          unsigned int* __restrict__ outb,
                                                          int n8) {
    int i = blockIdx.x * blockDim.x + threadIdx.x;
    if (i >= n8) return;
    const float4* p = (const float4*)in + (size_t)i * 2;
    float4 a = p[0], b = p[1];
    uint4 r;
    r.x = packbf(a.x, a.y);
    r.y = packbf(a.z, a.w);
    r.z = packbf(b.x, b.y);
    r.w = packbf(b.z, b.w);
    ((uint4*)outb)[i] = r;
}

// ---------------- pull aggregation (mean), bf16 rows ----------------

// F=128: one wave per node; lane owns feature pair (2*lane, 2*lane+1) = one uint.
__global__ __launch_bounds__(256) void pull_mean128_bf_kernel(
    const unsigned int* __restrict__ xb,   // [N][64] uints
    const int* __restrict__ row_ptr, const int* __restrict__ adj,
    unsigned int* __restrict__ aggb) {     // [N][64] uints
    int node = blockIdx.x * 4 + (threadIdx.x >> 6);
    if (node >= NN) return;
    int lane = threadIdx.x & 63;
    int beg = row_ptr[node], end = row_ptr[node + 1];
    float ax = 0.f, ay = 0.f;
    int p = beg;
    for (; p + 4 <= end; p += 4) {
        int s0 = adj[p + 0], s1 = adj[p + 1], s2 = adj[p + 2], s3 = adj[p + 3];
        unsigned int u0 = xb[(size_t)s0 * 64 + lane];
        unsigned int u1 = xb[(size_t)s1 * 64 + lane];
        unsigned int u2 = xb[(size_t)s2 * 64 + lane];
        unsigned int u3 = xb[(size_t)s3 * 64 + lane];
        ax += (bflo(u0) + bflo(u1)) + (bflo(u2) + bflo(u3));
        ay += (bfhi(u0) + bfhi(u1)) + (bfhi(u2) + bfhi(u3));
    }
    for (; p < end; ++p) {
        unsigned int u = xb[(size_t)adj[p] * 64 + lane];
        ax += bflo(u);
        ay += bfhi(u);
    }
    float inv = 1.0f / (float)(end > beg ? (end - beg) : 1);
    aggb[(size_t)node * 64 + lane] = packbf(ax * inv, ay * inv);
}

// F=64: one wave per node; lane owns one feature (ushort).
__global__ __launch_bounds__(256) void pull_mean64_bf_kernel(
    const unsigned short* __restrict__ zb,  // [N][64] bf16
    const int* __restrict__ row_ptr, const int* __restrict__ adj,
    float* __restrict__ aggout) {           // [N][64] fp32
    int node = blockIdx.x * 4 + (threadIdx.x >> 6);
    if (node >= NN) return;
    int lane = threadIdx.x & 63;
    int beg = row_ptr[node], end = row_ptr[node + 1];
    float acc = 0.f;
    int p = beg;
    for (; p + 4 <= end; p += 4) {
        int s0 = adj[p + 0], s1 = adj[p + 1], s2 = adj[p + 2], s3 = adj[p + 3];
        float v0 = bf2f(zb[(size_t)s0 * 64 + lane]);
        float v1 = bf2f(zb[(size_t)s1 * 64 + lane]);
        float v2 = bf2f(zb[(size_t)s2 * 64 + lane]);
        float v3 = bf2f(zb[(size_t)s3 * 64 + lane]);
        acc += (v0 + v1) + (v2 + v3);
    }
    for (; p < end; ++p) acc += bf2f(zb[(size_t)adj[p] * 64 + lane]);
    float inv = 1.0f / (float)(end > beg ? (end - beg) : 1);
    aggout[(size_t)node * 64 + lane] = acc * inv;
}

// ---------------- fused SAGE layer (H=128): out_bf = relu(agg@Wl + xin@Wr + b) ----------------
// A inputs bf16, weights fp32, compute fp32, output bf16.

__global__ __launch_bounds__(256) void sage_layer128_bf_kernel(
    const unsigned int* __restrict__ agg_u, const unsigned int* __restrict__ xin_u,
    const float* __restrict__ Wl, const float* __restrict__ Wr,
    const float* __restrict__ bias, unsigned int* __restrict__ out_u, int n_rows) {
    __shared__ float As[64][40];
    __shared__ float Bs[32][128];

    const int t    = threadIdx.x;
    const int row0 = blockIdx.x * 64;
    const int h0   = (t & 15) * 8;
    const int n0   = (t >> 4) * 4;

    float acc[4][8];
#pragma unroll
    for (int i = 0; i < 4; ++i)
#pragma unroll
        for (int j = 0; j < 8; ++j) acc[i][j] = 0.f;

    const int an = t >> 2;        // 0..63
    const int ak = (t & 3) * 8;   // 0,8,16,24
    const int bk = t >> 3;        // 0..31
    const int bh = (t & 7) * 16;  // 0..112

    for (int kt = 0; kt < 8; ++kt) {
        const int k0 = kt * 32;
        const unsigned int* Asrc = (k0 < 128) ? agg_u : xin_u;
        const float* Bsrc = (k0 < 128) ? Wl : Wr;
        const int ka = (k0 < 128) ? k0 : (k0 - 128);

        // A tile 64x32 from bf16
        {
            int r = row0 + an;
            uint4 v = make_uint4(0u, 0u, 0u, 0u);
            if (r < n_rows)
                v = *(const uint4*)(Asrc + (size_t)r * 64 + ((ka + ak) >> 1));
            float* q = &As[an][ak];
            q[0] = bflo(v.x); q[1] = bfhi(v.x);
            q[2] = bflo(v.y); q[3] = bfhi(v.y);
            q[4] = bflo(v.z); q[5] = bfhi(v.z);
            q[6] = bflo(v.w); q[7] = bfhi(v.w);
        }
        // B tile 32x128 (fp32 weights)
        {
            const float4* p = (const float4*)(Bsrc + (size_t)(ka + bk) * 128 + bh);
            float4* q = (float4*)(&Bs[bk][bh]);
            q[0] = p[0]; q[1] = p[1]; q[2] = p[2]; q[3] = p[3];
        }
        __syncthreads();

#pragma unroll
        for (int kk = 0; kk < 32; ++kk) {
            float a0 = As[n0 + 0][kk];
            float a1 = As[n0 + 1][kk];
            float a2 = As[n0 + 2][kk];
            float a3 = As[n0 + 3][kk];
            float4 bv0 = *(const float4*)(&Bs[kk][h0]);
            float4 bv1 = *(const float4*)(&Bs[kk][h0 + 4]);
            float bvals[8] = {bv0.x, bv0.y, bv0.z, bv0.w, bv1.x, bv1.y, bv1.z, bv1.w};
#pragma unroll
            for (int j = 0; j < 8; ++j) {
                acc[0][j] += a0 * bvals[j];
                acc[1][j] += a1 * bvals[j];
                acc[2][j] += a2 * bvals[j];
                acc[3][j] += a3 * bvals[j];
            }
        }
        __syncthreads();
    }

    float bv[8];
#pragma unroll
    for (int j = 0; j < 8; ++j) bv[j] = bias[h0 + j];
#pragma unroll
    for (int i = 0; i < 4; ++i) {
        int r = row0 + n0 + i;
        if (r < n_rows) {
            float vals[8];
#pragma unroll
            for (int j = 0; j < 8; ++j) vals[j] = fmaxf(acc[i][j] + bv[j], 0.f);
            uint4 w;
            w.x = packbf(vals[0], vals[1]);
            w.y = packbf(vals[2], vals[3]);
            w.z = packbf(vals[4], vals[5]);
            w.w = packbf(vals[6], vals[7]);
            *(uint4*)(out_u + (size_t)r * 64 + (h0 >> 1)) = w;
        }
    }
}

// ---------------- C[N,64] = A_bf[N,128] @ W[128,64]; MODE 0: bf16 out; MODE 1: fp32 out + add + bias ----------------

template <int MODE>
__global__ __launch_bounds__(256) void matmul64_bf_kernel(
    const unsigned int* __restrict__ A_u, const float* __restrict__ W,
    const float* __restrict__ addin, const float* __restrict__ bias,
    void* __restrict__ outp, int n_rows) {
    __shared__ float As[64][40];
    __shared__ float Bs[32][64];

    const int t    = threadIdx.x;
    const int row0 = blockIdx.x * 64;
    const int h0   = (t & 15) * 4;
    const int n0   = (t >> 4) * 4;

    float acc[4][4];
#pragma unroll
    for (int i = 0; i < 4; ++i)
#pragma unroll
        for (int j = 0; j < 4; ++j) acc[i][j] = 0.f;

    const int an = t >> 2;
    const int ak = (t & 3) * 8;
    const int bk = t >> 3;
    const int bh = (t & 7) * 8;

    for (int kt = 0; kt < 4; ++kt) {
        const int k0 = kt * 32;
        {
            int r = row0 + an;
            uint4 v = make_uint4(0u, 0u, 0u, 0u);
            if (r < n_rows)
                v = *(const uint4*)(A_u + (size_t)r * 64 + ((k0 + ak) >> 1));
            float* q = &As[an][ak];
            q[0] = bflo(v.x); q[1] = bfhi(v.x);
            q[2] = bflo(v.y); q[3] = bfhi(v.y);
            q[4] = bflo(v.z); q[5] = bfhi(v.z);
            q[6] = bflo(v.w); q[7] = bfhi(v.w);
        }
        {
            const float4* p = (const float4*)(W + (size_t)(k0 + bk) * 64 + bh);
            float4* q = (float4*)(&Bs[bk][bh]);
            q[0] = p[0]; q[1] = p[1];
        }
        __syncthreads();

#pragma unroll
        for (int kk = 0; kk < 32; ++kk) {
            float a0 = As[n0 + 0][kk];
            float a1 = As[n0 + 1][kk];
            float a2 = As[n0 + 2][kk];
            float a3 = As[n0 + 3][kk];
            float4 bvv = *(const float4*)(&Bs[kk][h0]);
            float bvals[4] = {bvv.x, bvv.y, bvv.z, bvv.w};
#pragma unroll
            for (int j = 0; j < 4; ++j) {
                acc[0][j] += a0 * bvals[j];
                acc[1][j] += a1 * bvals[j];
                acc[2][j] += a2 * bvals[j];
                acc[3][j] += a3 * bvals[j];
            }
        }
        __syncthreads();
    }

#pragma unroll
    for (int i = 0; i < 4; ++i) {
        int r = row0 + n0 + i;
        if (r < n_rows) {
            if (MODE == 0) {
                uint2 w;
                w.x = packbf(acc[i][0], acc[i][1]);
                w.y = packbf(acc[i][2], acc[i][3]);
                *(uint2*)((unsigned int*)outp + (size_t)r * 32 + (h0 >> 1)) = w;
            } else {
                float vals[4];
#pragma unroll
                for (int j = 0; j < 4; ++j)
                    vals[j] = acc[i][j] + addin[(size_t)r * 64 + h0 + j] + bias[h0 + j];
                *(float4*)((float*)outp + (size_t)r * 64 + h0) = *(float4*)vals;
            }
        }
    }
}

// ---------------- launcher ----------------

extern "C" void kernel_launch(void* const* d_in, const int* in_sizes, int n_in,
                              void* d_out, int out_size, void* d_ws, size_t ws_size,
                              hipStream_t stream) {
    (void)in_sizes; (void)n_in; (void)out_size; (void)ws_size;

    const float* x   = (const float*)d_in[0];
    const int* eidx  = (const int*)d_in[1];
    const int* src   = eidx;
    const int* dst   = eidx + NE;
    const float* W1l = (const float*)d_in[2];
    const float* W1r = (const float*)d_in[3];
    const float* b1  = (const float*)d_in[4];
    const float* W2l = (const float*)d_in[5];
    const float* W2r = (const float*)d_in[6];
    const float* b2  = (const float*)d_in[7];
    const float* W3l = (const float*)d_in[8];
    const float* W3r = (const float*)d_in[9];
    const float* b3  = (const float*)d_in[10];
    float* out = (float*)d_out;

    size_t off = 0;
    auto carve = [&](size_t bytes) -> void* {
        void* p = (char*)d_ws + off;
        off += (bytes + 255) & ~(size_t)255;
        return p;
    };
    int* count   = (int*)carve((size_t)NN * 4);
    int* row_ptr = (int*)carve((size_t)(NN + 1) * 4);
    int* cursor  = (int*)carve((size_t)NN * 4);
    int* bsum    = (int*)carve((size_t)NB_SCAN * 4);
    int* adj     = (int*)carve((size_t)NE * 4);
    unsigned int* x_bf   = (unsigned int*)carve((size_t)NN * 64 * 4);   // N x 128 bf16
    unsigned int* agg_bf = (unsigned int*)carve((size_t)NN * 64 * 4);
    unsigned int* h1_bf  = (unsigned int*)carve((size_t)NN * 64 * 4);
    unsigned int* h2_bf  = (unsigned int*)carve((size_t)NN * 64 * 4);
    unsigned int* z_bf   = (unsigned int*)carve((size_t)NN * 32 * 4);   // N x 64 bf16
    float* agg3          = (float*)carve((size_t)NN * 64 * 4);          // N x 64 fp32

    const int egrid = (NE + 255) / 256;
    const int ngrid = (NN + 255) / 256;
    const int mgrid = (NN + 63) / 64;   // 1563
    const int pgrid = (NN + 3) / 4;     // 25000
    const int cgrid = (NN * 16 + 255) / 256;  // convert: 1.6M threads

    // --- CSR build ---
    zero_int_kernel<<<ngrid, 256, 0, stream>>>(count, NN);
    count_kernel<<<egrid, 256, 0, stream>>>(dst, count);
    block_sum_kernel<<<NB_SCAN, 256, 0, stream>>>(count, bsum);
    scan_bsum_kernel<<<1, 64, 0, stream>>>(bsum, NB_SCAN);
    scan_block_kernel<<<NB_SCAN, 1024, 0, stream>>>(count, bsum, row_ptr, cursor);
    fill_adj_kernel<<<egrid, 256, 0, stream>>>(src, dst, cursor, adj);

    // --- convert x to bf16 ---
    f32_to_bf16_kernel<<<cgrid, 256, 0, stream>>>(x, x_bf, NN * 16);

    // --- layer 1 ---
    pull_mean128_bf_kernel<<<pgrid, 256, 0, stream>>>(x_bf, row_ptr, adj, agg_bf);
    sage_layer128_bf_kernel<<<mgrid, 256, 0, stream>>>(agg_bf, x_bf, W1l, W1r, b1, h1_bf, NN);

    // --- layer 2 ---
    pull_mean128_bf_kernel<<<pgrid, 256, 0, stream>>>(h1_bf, row_ptr, adj, agg_bf);
    sage_layer128_bf_kernel<<<mgrid, 256, 0, stream>>>(agg_bf, h1_bf, W2l, W2r, b2, h2_bf, NN);

    // --- layer 3: z = h2 @ W3l (bf16), pull, out = h2 @ W3r + agg3 + b3 ---
    matmul64_bf_kernel<0><<<mgrid, 256, 0, stream>>>(h2_bf, W3l, nullptr, nullptr, z_bf, NN);
    pull_mean64_bf_kernel<<<pgrid, 256, 0, stream>>>((const unsigned short*)z_bf, row_ptr, adj, agg3);
    matmul64_bf_kernel<1><<<mgrid, 256, 0, stream>>>(h2_bf, W3r, agg3, b3, out, NN);
}

// Round 3
// 480.440 us; speedup vs baseline: 1.9304x; 1.4216x over previous
//
#include <hip/hip_runtime.h>

#define NN 100000
#define NE 1600000
#define NB_SCAN 98   // ceil(NN/1024)
#define NPART (NN / 8)   // 12500 nodes per XCD group
#define GBLOCKS 256      // blocks per group

typedef __attribute__((ext_vector_type(8))) short bf16x8;
typedef __attribute__((ext_vector_type(4))) float f32x4;

// ---------------- bf16 helpers (stored as ushort/uint, math in fp32) ----------------

__device__ __forceinline__ unsigned short f2bf(float f) {
    unsigned int u = __float_as_uint(f);
    unsigned int r = u + 0x7fffu + ((u >> 16) & 1u);  // RNE
    return (unsigned short)(r >> 16);
}
__device__ __forceinline__ float bf2f(unsigned short h) {
    return __uint_as_float(((unsigned int)h) << 16);
}
__device__ __forceinline__ float bflo(unsigned int u) { return __uint_as_float(u << 16); }
__device__ __forceinline__ float bfhi(unsigned int u) { return __uint_as_float(u & 0xffff0000u); }
__device__ __forceinline__ unsigned int packbf(float lo, float hi) {
    return ((unsigned int)f2bf(hi) << 16) | (unsigned int)f2bf(lo);
}
__device__ __forceinline__ bf16x8 as_bf8(uint4 u) {
    union { uint4 u; bf16x8 h; } c;
    c.u = u;
    return c.h;
}

// ---------------- CSR build (XCD-partitioned count/fill) ----------------

__global__ void zero_int_kernel(int* __restrict__ p, int n) {
    int i = blockIdx.x * blockDim.x + threadIdx.x;
    if (i < n) p[i] = 0;
}

// 8 groups x 256 blocks; group g handles dst in [g*NPART, (g+1)*NPART)
__global__ __launch_bounds__(256) void count_part_kernel(const int* __restrict__ dst,
                                                         int* __restrict__ count) {
    int g = blockIdx.x & 7;
    int lo = g * NPART, hi = lo + NPART;
    int tid = (blockIdx.x >> 3) * 256 + threadIdx.x;
    for (int e = tid; e < NE; e += GBLOCKS * 256) {
        int d = dst[e];
        if (d >= lo && d < hi) atomicAdd(&count[d], 1);
    }
}

__global__ __launch_bounds__(256) void fill_part_kernel(const int* __restrict__ src,
                                                        const int* __restrict__ dst,
                                                        int* __restrict__ cursor,
                                                        int* __restrict__ adj) {
    int g = blockIdx.x & 7;
    int lo = g * NPART, hi = lo + NPART;
    int tid = (blockIdx.x >> 3) * 256 + threadIdx.x;
    for (int e = tid; e < NE; e += GBLOCKS * 256) {
        int d = dst[e];
        if (d >= lo && d < hi) {
            int pos = atomicAdd(&cursor[d], 1);
            adj[pos] = src[e];
        }
    }
}

__global__ __launch_bounds__(256) void block_sum_kernel(const int* __restrict__ count,
                                                        int* __restrict__ bsum) {
    __shared__ int sdata[256];
    int t = threadIdx.x;
    int base = blockIdx.x * 1024;
    int s = 0;
    for (int i = t; i < 1024; i += 256) {
        int idx = base + i;
        s += (idx < NN) ? count[idx] : 0;
    }
    sdata[t] = s;
    __syncthreads();
    for (int off = 128; off > 0; off >>= 1) {
        if (t < off) sdata[t] += sdata[t + off];
        __syncthreads();
    }
    if (t == 0) bsum[blockIdx.x] = sdata[0];
}

__global__ void scan_bsum_kernel(int* __restrict__ bsum, int nb) {
    if (blockIdx.x == 0 && threadIdx.x == 0) {
        int run = 0;
        for (int i = 0; i < nb; ++i) {
            int v = bsum[i];
            bsum[i] = run;
            run += v;
        }
    }
}

__global__ __launch_bounds__(1024) void scan_block_kernel(const int* __restrict__ count,
                                                          const int* __restrict__ bsum,
                                                          int* __restrict__ row_ptr,
                                                          int* __restrict__ cursor) {
    __shared__ int sdata[1024];
    int t = threadIdx.x;
    int idx = blockIdx.x * 1024 + t;
    int v = (idx < NN) ? count[idx] : 0;
    sdata[t] = v;
    __syncthreads();
    for (int off = 1; off < 1024; off <<= 1) {
        int add = (t >= off) ? sdata[t - off] : 0;
        __syncthreads();
        sdata[t] += add;
        __syncthreads();
    }
    if (idx < NN) {
        int excl = sdata[t] - v + bsum[blockIdx.x];
        row_ptr[idx] = excl;
        cursor[idx]  = excl;
        if (idx == NN - 1) row_ptr[NN] = excl + v;
    }
}

// ---------------- fp32 -> bf16 feature conversion (8 elems / thread) ----------------

__global__ __launch_bounds__(256) void f32_to_bf16_kernel(const float* __restrict__ in,
                                                          unsigned int* __restrict__ outb,
                                                          int n8) {
    int i = blockIdx.x * blockDim.x + threadIdx.x;
    if (i >= n8) return;
    const float4* p = (const float4*)in + (size_t)i * 2;
    float4 a = p[0], b = p[1];
    uint4 r;
    r.x = packbf(a.x, a.y);
    r.y = packbf(a.z, a.w);
    r.z = packbf(b.x, b.y);
    r.w = packbf(b.z, b.w);
    ((uint4*)outb)[i] = r;
}

// ---------------- weight -> MFMA B-fragment layout ----------------
// wfrag[(kt*(H/16)+nt)*64 + lane] (uint4 = 8 bf16), elem i = W[kt*32 + (lane>>4)*8 + i][nt*16 + (lane&15)]

__global__ __launch_bounds__(256) void wfrag_kernel(const float* __restrict__ W, int K, int H,
                                                    uint4* __restrict__ out) {
    int idx = blockIdx.x * blockDim.x + threadIdx.x;
    int total = (K >> 5) * (H >> 4) * 64;
    if (idx >= total) return;
    int lane = idx & 63;
    int tile = idx >> 6;
    int ntiles = H >> 4;
    int nt = tile % ntiles;
    int kt = tile / ntiles;
    int kbase = kt * 32 + (lane >> 4) * 8;
    int col = nt * 16 + (lane & 15);
    uint4 r;
    r.x = packbf(W[(size_t)(kbase + 0) * H + col], W[(size_t)(kbase + 1) * H + col]);
    r.y = packbf(W[(size_t)(kbase + 2) * H + col], W[(size_t)(kbase + 3) * H + col]);
    r.z = packbf(W[(size_t)(kbase + 4) * H + col], W[(size_t)(kbase + 5) * H + col]);
    r.w = packbf(W[(size_t)(kbase + 6) * H + col], W[(size_t)(kbase + 7) * H + col]);
    out[idx] = r;
}

// ---------------- pull aggregation (mean), bf16 rows ----------------

__global__ __launch_bounds__(256) void pull_mean128_bf_kernel(
    const unsigned int* __restrict__ xb, const int* __restrict__ row_ptr,
    const int* __restrict__ adj, unsigned int* __restrict__ aggb) {
    int node = blockIdx.x * 4 + (threadIdx.x >> 6);
    if (node >= NN) return;
    int lane = threadIdx.x & 63;
    int beg = row_ptr[node], end = row_ptr[node + 1];
    float ax = 0.f, ay = 0.f;
    int p = beg;
    for (; p + 4 <= end; p += 4) {
        int s0 = adj[p + 0], s1 = adj[p + 1], s2 = adj[p + 2], s3 = adj[p + 3];
        unsigned int u0 = xb[(size_t)s0 * 64 + lane];
        unsigned int u1 = xb[(size_t)s1 * 64 + lane];
        unsigned int u2 = xb[(size_t)s2 * 64 + lane];
        unsigned int u3 = xb[(size_t)s3 * 64 + lane];
        ax += (bflo(u0) + bflo(u1)) + (bflo(u2) + bflo(u3));
        ay += (bfhi(u0) + bfhi(u1)) + (bfhi(u2) + bfhi(u3));
    }
    for (; p < end; ++p) {
        unsigned int u = xb[(size_t)adj[p] * 64 + lane];
        ax += bflo(u);
        ay += bfhi(u);
    }
    float inv = 1.0f / (float)(end > beg ? (end - beg) : 1);
    aggb[(size_t)node * 64 + lane] = packbf(ax * inv, ay * inv);
}

__global__ __launch_bounds__(256) void pull_mean64_bf_kernel(
    const unsigned short* __restrict__ zb, const int* __restrict__ row_ptr,
    const int* __restrict__ adj, float* __restrict__ aggout) {
    int node = blockIdx.x * 4 + (threadIdx.x >> 6);
    if (node >= NN) return;
    int lane = threadIdx.x & 63;
    int beg = row_ptr[node], end = row_ptr[node + 1];
    float acc = 0.f;
    int p = beg;
    for (; p + 4 <= end; p += 4) {
        int s0 = adj[p + 0], s1 = adj[p + 1], s2 = adj[p + 2], s3 = adj[p + 3];
        float v0 = bf2f(zb[(size_t)s0 * 64 + lane]);
        float v1 = bf2f(zb[(size_t)s1 * 64 + lane]);
        float v2 = bf2f(zb[(size_t)s2 * 64 + lane]);
        float v3 = bf2f(zb[(size_t)s3 * 64 + lane]);
        acc += (v0 + v1) + (v2 + v3);
    }
    for (; p < end; ++p) acc += bf2f(zb[(size_t)adj[p] * 64 + lane]);
    float inv = 1.0f / (float)(end > beg ? (end - beg) : 1);
    aggout[(size_t)node * 64 + lane] = acc * inv;
}

// ---------------- MFMA SAGE layer (H=128): out = relu(agg@Wl + xin@Wr + b) ----------------
// 4 waves/block, 16 rows/wave, 64 rows/block. A-frags direct from global (bf16 rows),
// B-frags from pre-swizzled wfrag (kt 0..3 = Wl, kt 4..7 = Wr). No LDS.

__global__ __launch_bounds__(256) void sage_mfma_kernel(
    const uint4* __restrict__ aggA, const uint4* __restrict__ xinA,
    const uint4* __restrict__ wfrag, const float* __restrict__ bias,
    unsigned short* __restrict__ outb) {
    const int w = threadIdx.x >> 6;
    const int l = threadIdx.x & 63;
    const int r0 = blockIdx.x * 64 + w * 16;
    int arow = r0 + (l & 15);
    if (arow > NN - 1) arow = NN - 1;
    const int koff = l >> 4;  // which 16B chunk of the 64B k-step

    f32x4 acc[8];
#pragma unroll
    for (int nt = 0; nt < 8; ++nt) {
        f32x4 z = {0.f, 0.f, 0.f, 0.f};
        acc[nt] = z;
    }

#pragma unroll
    for (int kt = 0; kt < 8; ++kt) {
        const uint4* Ab = (kt < 4) ? aggA : xinA;
        const int ktl = kt & 3;
        bf16x8 av = as_bf8(Ab[(size_t)arow * 16 + ktl * 4 + koff]);
#pragma unroll
        for (int nt = 0; nt < 8; ++nt) {
            bf16x8 bv = as_bf8(wfrag[(kt * 8 + nt) * 64 + l]);
            acc[nt] = __builtin_amdgcn_mfma_f32_16x16x32_bf16(av, bv, acc[nt], 0, 0, 0);
        }
    }

    const int crow0 = r0 + ((l >> 4) << 2);
    const int ccol = l & 15;
#pragma unroll
    for (int nt = 0; nt < 8; ++nt) {
        float bb = bias[nt * 16 + ccol];
#pragma unroll
        for (int i = 0; i < 4; ++i) {
            int r = crow0 + i;
            if (r < NN) {
                float v = fmaxf(acc[nt][i] + bb, 0.f);
                outb[(size_t)r * 128 + nt * 16 + ccol] = f2bf(v);
            }
        }
    }
}

// ---------------- MFMA matmul (K=128 -> H=64) ----------------
// MODE 0: bf16 out.  MODE 1: fp32 out = acc + addin + bias.

template <int MODE>
__global__ __launch_bounds__(256) void mm64_mfma_kernel(
    const uint4* __restrict__ A, const uint4* __restrict__ wfrag,
    const float* __restrict__ addin, const float* __restrict__ bias,
    void* __restrict__ outp) {
    const int w = threadIdx.x >> 6;
    const int l = threadIdx.x & 63;
    const int r0 = blockIdx.x * 64 + w * 16;
    int arow = r0 + (l & 15);
    if (arow > NN - 1) arow = NN - 1;
    const int koff = l >> 4;

    f32x4 acc[4];
#pragma unroll
    for (int nt = 0; nt < 4; ++nt) {
        f32x4 z = {0.f, 0.f, 0.f, 0.f};
        acc[nt] = z;
    }

#pragma unroll
    for (int kt = 0; kt < 4; ++kt) {
        bf16x8 av = as_bf8(A[(size_t)arow * 16 + kt * 4 + koff]);
#pragma unroll
        for (int nt = 0; nt < 4; ++nt) {
            bf16x8 bv = as_bf8(wfrag[(kt * 4 + nt) * 64 + l]);
            acc[nt] = __builtin_amdgcn_mfma_f32_16x16x32_bf16(av, bv, acc[nt], 0, 0, 0);
        }
    }

    const int crow0 = r0 + ((l >> 4) << 2);
    const int ccol = l & 15;
#pragma unroll
    for (int nt = 0; nt < 4; ++nt) {
        int col = nt * 16 + ccol;
#pragma unroll
        for (int i = 0; i < 4; ++i) {
            int r = crow0 + i;
            if (r < NN) {
                if (MODE == 0) {
                    ((unsigned short*)outp)[(size_t)r * 64 + col] = f2bf(acc[nt][i]);
                } else {
                    float v = acc[nt][i] + addin[(size_t)r * 64 + col] + bias[col];
                    ((float*)outp)[(size_t)r * 64 + col] = v;
                }
            }
        }
    }
}

// ---------------- launcher ----------------

extern "C" void kernel_launch(void* const* d_in, const int* in_sizes, int n_in,
                              void* d_out, int out_size, void* d_ws, size_t ws_size,
                              hipStream_t stream) {
    (void)in_sizes; (void)n_in; (void)out_size; (void)ws_size;

    const float* x   = (const float*)d_in[0];
    const int* eidx  = (const int*)d_in[1];
    const int* src   = eidx;
    const int* dst   = eidx + NE;
    const float* W1l = (const float*)d_in[2];
    const float* W1r = (const float*)d_in[3];
    const float* b1  = (const float*)d_in[4];
    const float* W2l = (const float*)d_in[5];
    const float* W2r = (const float*)d_in[6];
    const float* b2  = (const float*)d_in[7];
    const float* W3l = (const float*)d_in[8];
    const float* W3r = (const float*)d_in[9];
    const float* b3  = (const float*)d_in[10];
    float* out = (float*)d_out;

    size_t off = 0;
    auto carve = [&](size_t bytes) -> void* {
        void* p = (char*)d_ws + off;
        off += (bytes + 255) & ~(size_t)255;
        return p;
    };
    int* count   = (int*)carve((size_t)NN * 4);
    int* row_ptr = (int*)carve((size_t)(NN + 1) * 4);
    int* cursor  = (int*)carve((size_t)NN * 4);
    int* bsum    = (int*)carve((size_t)NB_SCAN * 4);
    int* adj     = (int*)carve((size_t)NE * 4);
    unsigned int* x_bf   = (unsigned int*)carve((size_t)NN * 64 * 4);  // N x 128 bf16
    unsigned int* agg_bf = (unsigned int*)carve((size_t)NN * 64 * 4);
    unsigned int* h1_bf  = (unsigned int*)carve((size_t)NN * 64 * 4);
    unsigned int* h2_bf  = (unsigned int*)carve((size_t)NN * 64 * 4);
    unsigned int* z_bf   = (unsigned int*)carve((size_t)NN * 32 * 4);  // N x 64 bf16
    float* agg3          = (float*)carve((size_t)NN * 64 * 4);         // N x 64 fp32
    uint4* wf1  = (uint4*)carve((size_t)8 * 8 * 64 * 16);  // layer1 Wl+Wr frags (64KB)
    uint4* wf2  = (uint4*)carve((size_t)8 * 8 * 64 * 16);
    uint4* wf3l = (uint4*)carve((size_t)4 * 4 * 64 * 16);  // 16KB
    uint4* wf3r = (uint4*)carve((size_t)4 * 4 * 64 * 16);

    const int ngrid = (NN + 255) / 256;
    const int mgrid = (NN + 63) / 64;   // 1563
    const int pgrid = (NN + 3) / 4;     // 25000
    const int cgrid = (NN * 16 + 255) / 256;
    const int wgrid128 = (4 * 8 * 64 + 255) / 256;  // per 128x128 weight: 2048 threads
    const int wgrid64  = (4 * 4 * 64 + 255) / 256;  // per 128x64 weight: 1024 threads

    // --- CSR build (XCD-partitioned) ---
    zero_int_kernel<<<ngrid, 256, 0, stream>>>(count, NN);
    count_part_kernel<<<8 * GBLOCKS, 256, 0, stream>>>(dst, count);
    block_sum_kernel<<<NB_SCAN, 256, 0, stream>>>(count, bsum);
    scan_bsum_kernel<<<1, 64, 0, stream>>>(bsum, NB_SCAN);
    scan_block_kernel<<<NB_SCAN, 1024, 0, stream>>>(count, bsum, row_ptr, cursor);
    fill_part_kernel<<<8 * GBLOCKS, 256, 0, stream>>>(src, dst, cursor, adj);

    // --- conversions: x -> bf16, weights -> MFMA frag layout ---
    f32_to_bf16_kernel<<<cgrid, 256, 0, stream>>>(x, x_bf, NN * 16);
    wfrag_kernel<<<wgrid128, 256, 0, stream>>>(W1l, 128, 128, wf1);
    wfrag_kernel<<<wgrid128, 256, 0, stream>>>(W1r, 128, 128, wf1 + 4 * 8 * 64);
    wfrag_kernel<<<wgrid128, 256, 0, stream>>>(W2l, 128, 128, wf2);
    wfrag_kernel<<<wgrid128, 256, 0, stream>>>(W2r, 128, 128, wf2 + 4 * 8 * 64);
    wfrag_kernel<<<wgrid64, 256, 0, stream>>>(W3l, 128, 64, wf3l);
    wfrag_kernel<<<wgrid64, 256, 0, stream>>>(W3r, 128, 64, wf3r);

    // --- layer 1 ---
    pull_mean128_bf_kernel<<<pgrid, 256, 0, stream>>>(x_bf, row_ptr, adj, agg_bf);
    sage_mfma_kernel<<<mgrid, 256, 0, stream>>>((const uint4*)agg_bf, (const uint4*)x_bf,
                                                wf1, b1, (unsigned short*)h1_bf);
    // --- layer 2 ---
    pull_mean128_bf_kernel<<<pgrid, 256, 0, stream>>>(h1_bf, row_ptr, adj, agg_bf);
    sage_mfma_kernel<<<mgrid, 256, 0, stream>>>((const uint4*)agg_bf, (const uint4*)h1_bf,
                                                wf2, b2, (unsigned short*)h2_bf);
    // --- layer 3: z = h2 @ W3l (bf16), pull, out = h2 @ W3r + agg3 + b3 ---
    mm64_mfma_kernel<0><<<mgrid, 256, 0, stream>>>((const uint4*)h2_bf, wf3l, nullptr, nullptr, z_bf);
    pull_mean64_bf_kernel<<<pgrid, 256, 0, stream>>>((const unsigned short*)z_bf, row_ptr, adj, agg3);
    mm64_mfma_kernel<1><<<mgrid, 256, 0, stream>>>((const uint4*)h2_bf, wf3r, agg3, b3, out);
}

// Round 4
// 443.864 us; speedup vs baseline: 2.0895x; 1.0824x over previous
//
#include <hip/hip_runtime.h>

#define NN 100000
#define NE 1600000
#define NB_SCAN 98   // ceil(NN/1024)
#define NPART (NN / 8)   // 12500 nodes per XCD group
#define GBLOCKS 256      // blocks per group

typedef __attribute__((ext_vector_type(8))) short bf16x8;
typedef __attribute__((ext_vector_type(4))) float f32x4;

// ---------------- bf16 helpers (stored as ushort/uint, math in fp32) ----------------

__device__ __forceinline__ unsigned short f2bf(float f) {
    unsigned int u = __float_as_uint(f);
    unsigned int r = u + 0x7fffu + ((u >> 16) & 1u);  // RNE
    return (unsigned short)(r >> 16);
}
__device__ __forceinline__ float bf2f(unsigned short h) {
    return __uint_as_float(((unsigned int)h) << 16);
}
__device__ __forceinline__ float bflo(unsigned int u) { return __uint_as_float(u << 16); }
__device__ __forceinline__ float bfhi(unsigned int u) { return __uint_as_float(u & 0xffff0000u); }
__device__ __forceinline__ unsigned int packbf(float lo, float hi) {
    return ((unsigned int)f2bf(hi) << 16) | (unsigned int)f2bf(lo);
}
__device__ __forceinline__ bf16x8 as_bf8(uint4 u) {
    union { uint4 u; bf16x8 h; } c;
    c.u = u;
    return c.h;
}

// ---------------- CSR build (XCD-partitioned count/fill, NT streaming reads) ----------------

// 8 groups x 256 blocks; group g handles dst in [g*NPART, (g+1)*NPART)
__global__ __launch_bounds__(256) void count_part_kernel(const int* __restrict__ dst,
                                                         int* __restrict__ count) {
    int g = blockIdx.x & 7;
    int lo = g * NPART, hi = lo + NPART;
    int tid = (blockIdx.x >> 3) * 256 + threadIdx.x;
    for (int e = tid; e < NE; e += GBLOCKS * 256) {
        int d = __builtin_nontemporal_load(dst + e);
        if (d >= lo && d < hi) atomicAdd(&count[d], 1);
    }
}

__global__ __launch_bounds__(256) void fill_part_kernel(const int* __restrict__ src,
                                                        const int* __restrict__ dst,
                                                        int* __restrict__ cursor,
                                                        int* __restrict__ adj) {
    int g = blockIdx.x & 7;
    int lo = g * NPART, hi = lo + NPART;
    int tid = (blockIdx.x >> 3) * 256 + threadIdx.x;
    for (int e = tid; e < NE; e += GBLOCKS * 256) {
        int d = __builtin_nontemporal_load(dst + e);
        if (d >= lo && d < hi) {
            int pos = atomicAdd(&cursor[d], 1);
            adj[pos] = src[e];   // src read only for in-range edges (1/8 density)
        }
    }
}

__global__ __launch_bounds__(256) void block_sum_kernel(const int* __restrict__ count,
                                                        int* __restrict__ bsum) {
    __shared__ int sdata[256];
    int t = threadIdx.x;
    int base = blockIdx.x * 1024;
    int s = 0;
    for (int i = t; i < 1024; i += 256) {
        int idx = base + i;
        s += (idx < NN) ? count[idx] : 0;
    }
    sdata[t] = s;
    __syncthreads();
    for (int off = 128; off > 0; off >>= 1) {
        if (t < off) sdata[t] += sdata[t + off];
        __syncthreads();
    }
    if (t == 0) bsum[blockIdx.x] = sdata[0];
}

__global__ void scan_bsum_kernel(int* __restrict__ bsum, int nb) {
    if (blockIdx.x == 0 && threadIdx.x == 0) {
        int run = 0;
        for (int i = 0; i < nb; ++i) {
            int v = bsum[i];
            bsum[i] = run;
            run += v;
        }
    }
}

__global__ __launch_bounds__(1024) void scan_block_kernel(const int* __restrict__ count,
                                                          const int* __restrict__ bsum,
                                                          int* __restrict__ row_ptr,
                                                          int* __restrict__ cursor) {
    __shared__ int sdata[1024];
    int t = threadIdx.x;
    int idx = blockIdx.x * 1024 + t;
    int v = (idx < NN) ? count[idx] : 0;
    sdata[t] = v;
    __syncthreads();
    for (int off = 1; off < 1024; off <<= 1) {
        int add = (t >= off) ? sdata[t - off] : 0;
        __syncthreads();
        sdata[t] += add;
        __syncthreads();
    }
    if (idx < NN) {
        int excl = sdata[t] - v + bsum[blockIdx.x];
        row_ptr[idx] = excl;
        cursor[idx]  = excl;
        if (idx == NN - 1) row_ptr[NN] = excl + v;
    }
}

// ---------------- fp32 -> bf16 feature conversion (8 elems / thread) ----------------

__global__ __launch_bounds__(256) void f32_to_bf16_kernel(const float* __restrict__ in,
                                                          unsigned int* __restrict__ outb,
                                                          int n8) {
    int i = blockIdx.x * blockDim.x + threadIdx.x;
    if (i >= n8) return;
    const float4* p = (const float4*)in + (size_t)i * 2;
    float4 a = p[0], b = p[1];
    uint4 r;
    r.x = packbf(a.x, a.y);
    r.y = packbf(a.z, a.w);
    r.z = packbf(b.x, b.y);
    r.w = packbf(b.z, b.w);
    ((uint4*)outb)[i] = r;
}

// ---------------- all weights -> MFMA B-fragment layout, one launch ----------------
// frag[(kt*(H/16)+nt)*64 + lane], elem i = W[kt*32 + (lane>>4)*8 + i][nt*16 + (lane&15)]

__device__ __forceinline__ void wfrag_one(const float* __restrict__ W, int H, int idx,
                                          uint4* __restrict__ out) {
    int lane = idx & 63;
    int tile = idx >> 6;
    int ntiles = H >> 4;
    int nt = tile % ntiles;
    int kt = tile / ntiles;
    int kbase = kt * 32 + (lane >> 4) * 8;
    int col = nt * 16 + (lane & 15);
    uint4 r;
    r.x = packbf(W[(size_t)(kbase + 0) * H + col], W[(size_t)(kbase + 1) * H + col]);
    r.y = packbf(W[(size_t)(kbase + 2) * H + col], W[(size_t)(kbase + 3) * H + col]);
    r.z = packbf(W[(size_t)(kbase + 4) * H + col], W[(size_t)(kbase + 5) * H + col]);
    r.w = packbf(W[(size_t)(kbase + 6) * H + col], W[(size_t)(kbase + 7) * H + col]);
    out[idx] = r;
}

// ranges (uint4 units): [0,2048) W1l->wf1, [2048,4096) W1r->wf1+2048,
// [4096,6144) W2l->wf2, [6144,8192) W2r->wf2+2048, [8192,9216) W3l->wf3l, [9216,10240) W3r->wf3r
__global__ __launch_bounds__(256) void wfrag_all_kernel(
    const float* __restrict__ W1l, const float* __restrict__ W1r,
    const float* __restrict__ W2l, const float* __restrict__ W2r,
    const float* __restrict__ W3l, const float* __restrict__ W3r,
    uint4* __restrict__ wf1, uint4* __restrict__ wf2,
    uint4* __restrict__ wf3l, uint4* __restrict__ wf3r) {
    int idx = blockIdx.x * blockDim.x + threadIdx.x;
    if (idx < 2048)       wfrag_one(W1l, 128, idx, wf1);
    else if (idx < 4096)  wfrag_one(W1r, 128, idx - 2048, wf1 + 2048);
    else if (idx < 6144)  wfrag_one(W2l, 128, idx - 4096, wf2);
    else if (idx < 8192)  wfrag_one(W2r, 128, idx - 6144, wf2 + 2048);
    else if (idx < 9216)  wfrag_one(W3l, 64, idx - 8192, wf3l);
    else if (idx < 10240) wfrag_one(W3r, 64, idx - 9216, wf3r);
}

// ---------------- pull aggregation (mean), bf16 rows, 16 lanes/edge ----------------
// F=128: row = 16 uint4. Wave = 4 groups of 16 lanes; group g handles edges base+g, base+g+4.

__global__ __launch_bounds__(256) void pull_mean128_bf_kernel(
    const uint4* __restrict__ xb4, const int* __restrict__ row_ptr,
    const int* __restrict__ adj, uint4* __restrict__ aggb4) {
    int node = blockIdx.x * 4 + (threadIdx.x >> 6);
    int l = threadIdx.x & 63;
    int g = l >> 4;   // 0..3
    int i = l & 15;   // 16B chunk of the row
    int beg = row_ptr[node], end = row_ptr[node + 1];
    float acc[8];
#pragma unroll
    for (int j = 0; j < 8; ++j) acc[j] = 0.f;

    for (int base = beg; base < end; base += 8) {
        int e0 = base + g;
        int e1 = base + 4 + g;
        bool v0 = e0 < end, v1 = e1 < end;
        int s0 = v0 ? adj[e0] : 0;
        int s1 = v1 ? adj[e1] : 0;
        uint4 u0 = xb4[(size_t)s0 * 16 + i];
        uint4 u1 = xb4[(size_t)s1 * 16 + i];
        float m0 = v0 ? 1.f : 0.f;
        float m1 = v1 ? 1.f : 0.f;
        acc[0] = fmaf(m0, bflo(u0.x), acc[0]);
        acc[1] = fmaf(m0, bfhi(u0.x), acc[1]);
        acc[2] = fmaf(m0, bflo(u0.y), acc[2]);
        acc[3] = fmaf(m0, bfhi(u0.y), acc[3]);
        acc[4] = fmaf(m0, bflo(u0.z), acc[4]);
        acc[5] = fmaf(m0, bfhi(u0.z), acc[5]);
        acc[6] = fmaf(m0, bflo(u0.w), acc[6]);
        acc[7] = fmaf(m0, bfhi(u0.w), acc[7]);
        acc[0] = fmaf(m1, bflo(u1.x), acc[0]);
        acc[1] = fmaf(m1, bfhi(u1.x), acc[1]);
        acc[2] = fmaf(m1, bflo(u1.y), acc[2]);
        acc[3] = fmaf(m1, bfhi(u1.y), acc[3]);
        acc[4] = fmaf(m1, bflo(u1.z), acc[4]);
        acc[5] = fmaf(m1, bfhi(u1.z), acc[5]);
        acc[6] = fmaf(m1, bflo(u1.w), acc[6]);
        acc[7] = fmaf(m1, bfhi(u1.w), acc[7]);
    }

#pragma unroll
    for (int j = 0; j < 8; ++j) {
        acc[j] += __shfl_xor(acc[j], 16);
        acc[j] += __shfl_xor(acc[j], 32);
    }
    if (g == 0) {
        float inv = 1.0f / (float)(end > beg ? (end - beg) : 1);
        uint4 r;
        r.x = packbf(acc[0] * inv, acc[1] * inv);
        r.y = packbf(acc[2] * inv, acc[3] * inv);
        r.z = packbf(acc[4] * inv, acc[5] * inv);
        r.w = packbf(acc[6] * inv, acc[7] * inv);
        aggb4[(size_t)node * 16 + i] = r;
    }
}

// F=64: row = 16 uint2 (128 B). Same structure, fp32 output for the final add.

__global__ __launch_bounds__(256) void pull_mean64_bf_kernel(
    const uint2* __restrict__ zb2, const int* __restrict__ row_ptr,
    const int* __restrict__ adj, float* __restrict__ aggout) {
    int node = blockIdx.x * 4 + (threadIdx.x >> 6);
    int l = threadIdx.x & 63;
    int g = l >> 4;
    int i = l & 15;
    int beg = row_ptr[node], end = row_ptr[node + 1];
    float acc[4];
#pragma unroll
    for (int j = 0; j < 4; ++j) acc[j] = 0.f;

    for (int base = beg; base < end; base += 8) {
        int e0 = base + g;
        int e1 = base + 4 + g;
        bool v0 = e0 < end, v1 = e1 < end;
        int s0 = v0 ? adj[e0] : 0;
        int s1 = v1 ? adj[e1] : 0;
        uint2 u0 = zb2[(size_t)s0 * 16 + i];
        uint2 u1 = zb2[(size_t)s1 * 16 + i];
        float m0 = v0 ? 1.f : 0.f;
        float m1 = v1 ? 1.f : 0.f;
        acc[0] = fmaf(m0, bflo(u0.x), acc[0]);
        acc[1] = fmaf(m0, bfhi(u0.x), acc[1]);
        acc[2] = fmaf(m0, bflo(u0.y), acc[2]);
        acc[3] = fmaf(m0, bfhi(u0.y), acc[3]);
        acc[0] = fmaf(m1, bflo(u1.x), acc[0]);
        acc[1] = fmaf(m1, bfhi(u1.x), acc[1]);
        acc[2] = fmaf(m1, bflo(u1.y), acc[2]);
        acc[3] = fmaf(m1, bfhi(u1.y), acc[3]);
    }

#pragma unroll
    for (int j = 0; j < 4; ++j) {
        acc[j] += __shfl_xor(acc[j], 16);
        acc[j] += __shfl_xor(acc[j], 32);
    }
    if (g == 0) {
        float inv = 1.0f / (float)(end > beg ? (end - beg) : 1);
        float4 r;
        r.x = acc[0] * inv;
        r.y = acc[1] * inv;
        r.z = acc[2] * inv;
        r.w = acc[3] * inv;
        *(float4*)(aggout + (size_t)node * 64 + i * 4) = r;
    }
}

// ---------------- MFMA SAGE layer (H=128): out = relu(agg@Wl + xin@Wr + b) ----------------

__global__ __launch_bounds__(256) void sage_mfma_kernel(
    const uint4* __restrict__ aggA, const uint4* __restrict__ xinA,
    const uint4* __restrict__ wfrag, const float* __restrict__ bias,
    unsigned short* __restrict__ outb) {
    const int w = threadIdx.x >> 6;
    const int l = threadIdx.x & 63;
    const int r0 = blockIdx.x * 64 + w * 16;
    int arow = r0 + (l & 15);
    if (arow > NN - 1) arow = NN - 1;
    const int koff = l >> 4;

    f32x4 acc[8];
#pragma unroll
    for (int nt = 0; nt < 8; ++nt) {
        f32x4 z = {0.f, 0.f, 0.f, 0.f};
        acc[nt] = z;
    }

#pragma unroll
    for (int kt = 0; kt < 8; ++kt) {
        const uint4* Ab = (kt < 4) ? aggA : xinA;
        const int ktl = kt & 3;
        bf16x8 av = as_bf8(Ab[(size_t)arow * 16 + ktl * 4 + koff]);
#pragma unroll
        for (int nt = 0; nt < 8; ++nt) {
            bf16x8 bv = as_bf8(wfrag[(kt * 8 + nt) * 64 + l]);
            acc[nt] = __builtin_amdgcn_mfma_f32_16x16x32_bf16(av, bv, acc[nt], 0, 0, 0);
        }
    }

    const int crow0 = r0 + ((l >> 4) << 2);
    const int ccol = l & 15;
#pragma unroll
    for (int nt = 0; nt < 8; ++nt) {
        float bb = bias[nt * 16 + ccol];
#pragma unroll
        for (int i = 0; i < 4; ++i) {
            int r = crow0 + i;
            if (r < NN) {
                float v = fmaxf(acc[nt][i] + bb, 0.f);
                outb[(size_t)r * 128 + nt * 16 + ccol] = f2bf(v);
            }
        }
    }
}

// ---------------- MFMA matmul (K=128 -> H=64) ----------------

template <int MODE>
__global__ __launch_bounds__(256) void mm64_mfma_kernel(
    const uint4* __restrict__ A, const uint4* __restrict__ wfrag,
    const float* __restrict__ addin, const float* __restrict__ bias,
    void* __restrict__ outp) {
    const int w = threadIdx.x >> 6;
    const int l = threadIdx.x & 63;
    const int r0 = blockIdx.x * 64 + w * 16;
    int arow = r0 + (l & 15);
    if (arow > NN - 1) arow = NN - 1;
    const int koff = l >> 4;

    f32x4 acc[4];
#pragma unroll
    for (int nt = 0; nt < 4; ++nt) {
        f32x4 z = {0.f, 0.f, 0.f, 0.f};
        acc[nt] = z;
    }

#pragma unroll
    for (int kt = 0; kt < 4; ++kt) {
        bf16x8 av = as_bf8(A[(size_t)arow * 16 + kt * 4 + koff]);
#pragma unroll
        for (int nt = 0; nt < 4; ++nt) {
            bf16x8 bv = as_bf8(wfrag[(kt * 4 + nt) * 64 + l]);
            acc[nt] = __builtin_amdgcn_mfma_f32_16x16x32_bf16(av, bv, acc[nt], 0, 0, 0);
        }
    }

    const int crow0 = r0 + ((l >> 4) << 2);
    const int ccol = l & 15;
#pragma unroll
    for (int nt = 0; nt < 4; ++nt) {
        int col = nt * 16 + ccol;
#pragma unroll
        for (int i = 0; i < 4; ++i) {
            int r = crow0 + i;
            if (r < NN) {
                if (MODE == 0) {
                    ((unsigned short*)outp)[(size_t)r * 64 + col] = f2bf(acc[nt][i]);
                } else {
                    float v = acc[nt][i] + addin[(size_t)r * 64 + col] + bias[col];
                    ((float*)outp)[(size_t)r * 64 + col] = v;
                }
            }
        }
    }
}

// ---------------- launcher ----------------

extern "C" void kernel_launch(void* const* d_in, const int* in_sizes, int n_in,
                              void* d_out, int out_size, void* d_ws, size_t ws_size,
                              hipStream_t stream) {
    (void)in_sizes; (void)n_in; (void)out_size; (void)ws_size;

    const float* x   = (const float*)d_in[0];
    const int* eidx  = (const int*)d_in[1];
    const int* src   = eidx;
    const int* dst   = eidx + NE;
    const float* W1l = (const float*)d_in[2];
    const float* W1r = (const float*)d_in[3];
    const float* b1  = (const float*)d_in[4];
    const float* W2l = (const float*)d_in[5];
    const float* W2r = (const float*)d_in[6];
    const float* b2  = (const float*)d_in[7];
    const float* W3l = (const float*)d_in[8];
    const float* W3r = (const float*)d_in[9];
    const float* b3  = (const float*)d_in[10];
    float* out = (float*)d_out;

    size_t off = 0;
    auto carve = [&](size_t bytes) -> void* {
        void* p = (char*)d_ws + off;
        off += (bytes + 255) & ~(size_t)255;
        return p;
    };
    int* count   = (int*)carve((size_t)NN * 4);
    int* row_ptr = (int*)carve((size_t)(NN + 1) * 4);
    int* cursor  = (int*)carve((size_t)NN * 4);
    int* bsum    = (int*)carve((size_t)NB_SCAN * 4);
    int* adj     = (int*)carve((size_t)NE * 4);
    unsigned int* x_bf   = (unsigned int*)carve((size_t)NN * 64 * 4);  // N x 128 bf16
    unsigned int* agg_bf = (unsigned int*)carve((size_t)NN * 64 * 4);
    unsigned int* h1_bf  = (unsigned int*)carve((size_t)NN * 64 * 4);
    unsigned int* h2_bf  = (unsigned int*)carve((size_t)NN * 64 * 4);
    unsigned int* z_bf   = (unsigned int*)carve((size_t)NN * 32 * 4);  // N x 64 bf16
    float* agg3          = (float*)carve((size_t)NN * 64 * 4);         // N x 64 fp32
    uint4* wf1  = (uint4*)carve((size_t)8 * 8 * 64 * 16);
    uint4* wf2  = (uint4*)carve((size_t)8 * 8 * 64 * 16);
    uint4* wf3l = (uint4*)carve((size_t)4 * 4 * 64 * 16);
    uint4* wf3r = (uint4*)carve((size_t)4 * 4 * 64 * 16);

    const int mgrid = (NN + 63) / 64;   // 1563
    const int pgrid = (NN + 3) / 4;     // 25000
    const int cgrid = (NN * 16 + 255) / 256;

    // --- CSR build (XCD-partitioned, NT streaming) ---
    hipMemsetAsync(count, 0, (size_t)NN * 4, stream);
    count_part_kernel<<<8 * GBLOCKS, 256, 0, stream>>>(dst, count);
    block_sum_kernel<<<NB_SCAN, 256, 0, stream>>>(count, bsum);
    scan_bsum_kernel<<<1, 64, 0, stream>>>(bsum, NB_SCAN);
    scan_block_kernel<<<NB_SCAN, 1024, 0, stream>>>(count, bsum, row_ptr, cursor);
    fill_part_kernel<<<8 * GBLOCKS, 256, 0, stream>>>(src, dst, cursor, adj);

    // --- conversions ---
    f32_to_bf16_kernel<<<cgrid, 256, 0, stream>>>(x, x_bf, NN * 16);
    wfrag_all_kernel<<<40, 256, 0, stream>>>(W1l, W1r, W2l, W2r, W3l, W3r, wf1, wf2, wf3l, wf3r);

    // --- layer 1 ---
    pull_mean128_bf_kernel<<<pgrid, 256, 0, stream>>>((const uint4*)x_bf, row_ptr, adj, (uint4*)agg_bf);
    sage_mfma_kernel<<<mgrid, 256, 0, stream>>>((const uint4*)agg_bf, (const uint4*)x_bf,
                                                wf1, b1, (unsigned short*)h1_bf);
    // --- layer 2 ---
    pull_mean128_bf_kernel<<<pgrid, 256, 0, stream>>>((const uint4*)h1_bf, row_ptr, adj, (uint4*)agg_bf);
    sage_mfma_kernel<<<mgrid, 256, 0, stream>>>((const uint4*)agg_bf, (const uint4*)h1_bf,
                                                wf2, b2, (unsigned short*)h2_bf);
    // --- layer 3: z = h2 @ W3l (bf16), pull, out = h2 @ W3r + agg3 + b3 ---
    mm64_mfma_kernel<0><<<mgrid, 256, 0, stream>>>((const uint4*)h2_bf, wf3l, nullptr, nullptr, z_bf);
    pull_mean64_bf_kernel<<<pgrid, 256, 0, stream>>>((const uint2*)z_bf, row_ptr, adj, agg3);
    mm64_mfma_kernel<1><<<mgrid, 256, 0, stream>>>((const uint4*)h2_bf, wf3r, agg3, b3, out);
}

// Round 5
// 437.226 us; speedup vs baseline: 2.1212x; 1.0152x over previous
//
#include <hip/hip_runtime.h>

#define NN 100000
#define NE 1600000
#define NB_SCAN 98       // ceil(NN/1024)
#define NPART (NN / 8)   // 12500 nodes per partition
#define GBLOCKS 256      // blocks per group in fill
#define NBLK_BUCKET 512
#define CHUNK (NE / NBLK_BUCKET)  // 3125
#define CAPB 210000      // bucket capacity (expected ~200K, uniform dst)

typedef __attribute__((ext_vector_type(8))) short bf16x8;
typedef __attribute__((ext_vector_type(4))) float f32x4;

// ---------------- bf16 helpers (stored as ushort/uint, math in fp32) ----------------

__device__ __forceinline__ unsigned short f2bf(float f) {
    unsigned int u = __float_as_uint(f);
    unsigned int r = u + 0x7fffu + ((u >> 16) & 1u);  // RNE
    return (unsigned short)(r >> 16);
}
__device__ __forceinline__ float bflo(unsigned int u) { return __uint_as_float(u << 16); }
__device__ __forceinline__ float bfhi(unsigned int u) { return __uint_as_float(u & 0xffff0000u); }
__device__ __forceinline__ unsigned int packbf(float lo, float hi) {
    return ((unsigned int)f2bf(hi) << 16) | (unsigned int)f2bf(lo);
}
__device__ __forceinline__ bf16x8 as_bf8(uint4 u) {
    union { uint4 u; bf16x8 h; } c;
    c.u = u;
    return c.h;
}

// ---------------- CSR build: bucket pass ----------------
// One streaming pass over edges. Per-block LDS histogram over 8 dst partitions,
// one gcursor bump per partition per block, dense chunk writes into buckets.
// Degree counts done here too (fire-and-forget atomics).

__global__ __launch_bounds__(256) void bucket_count_kernel(
    const int* __restrict__ src, const int* __restrict__ dst,
    int* __restrict__ count, int* __restrict__ gcursor,
    uint2* __restrict__ buckets) {
    __shared__ int hist[8];
    __shared__ int base[8];
    int t = threadIdx.x;
    if (t < 8) hist[t] = 0;
    __syncthreads();
    int e0 = blockIdx.x * CHUNK;
    int e1 = e0 + CHUNK;
    for (int e = e0 + t; e < e1; e += 256) {
        int d = dst[e];
        atomicAdd(&hist[d / NPART], 1);
        atomicAdd(&count[d], 1);
    }
    __syncthreads();
    if (t < 8) {
        base[t] = atomicAdd(&gcursor[t], hist[t]);
        hist[t] = 0;
    }
    __syncthreads();
    for (int e = e0 + t; e < e1; e += 256) {
        int d = dst[e];
        int s = src[e];
        int p = d / NPART;
        int slot = atomicAdd(&hist[p], 1);
        buckets[(size_t)p * CAPB + base[p] + slot] = make_uint2((unsigned)s, (unsigned)d);
    }
}

// ---------------- CSR build: per-partition fill (XCD-local working set) ----------------

__global__ __launch_bounds__(256) void fill_bucket_kernel(
    const uint2* __restrict__ buckets, const int* __restrict__ gcursor,
    int* __restrict__ cursor, int* __restrict__ adj) {
    int g = blockIdx.x & 7;
    int n = gcursor[g];
    const uint2* b = buckets + (size_t)g * CAPB;
    int tid = (blockIdx.x >> 3) * 256 + threadIdx.x;
    for (int i = tid; i < n; i += GBLOCKS * 256) {
        uint2 pr = b[i];
        int pos = atomicAdd(&cursor[pr.y], 1);
        adj[pos] = (int)pr.x;
    }
}

// ---------------- scans ----------------

__global__ __launch_bounds__(256) void block_sum_kernel(const int* __restrict__ count,
                                                        int* __restrict__ bsum) {
    __shared__ int sdata[256];
    int t = threadIdx.x;
    int base = blockIdx.x * 1024;
    int s = 0;
    for (int i = t; i < 1024; i += 256) {
        int idx = base + i;
        s += (idx < NN) ? count[idx] : 0;
    }
    sdata[t] = s;
    __syncthreads();
    for (int off = 128; off > 0; off >>= 1) {
        if (t < off) sdata[t] += sdata[t + off];
        __syncthreads();
    }
    if (t == 0) bsum[blockIdx.x] = sdata[0];
}

__global__ void scan_bsum_kernel(int* __restrict__ bsum, int nb) {
    if (blockIdx.x == 0 && threadIdx.x == 0) {
        int run = 0;
        for (int i = 0; i < nb; ++i) {
            int v = bsum[i];
            bsum[i] = run;
            run += v;
        }
    }
}

__global__ __launch_bounds__(1024) void scan_block_kernel(const int* __restrict__ count,
                                                          const int* __restrict__ bsum,
                                                          int* __restrict__ row_ptr,
                                                          int* __restrict__ cursor) {
    __shared__ int sdata[1024];
    int t = threadIdx.x;
    int idx = blockIdx.x * 1024 + t;
    int v = (idx < NN) ? count[idx] : 0;
    sdata[t] = v;
    __syncthreads();
    for (int off = 1; off < 1024; off <<= 1) {
        int add = (t >= off) ? sdata[t - off] : 0;
        __syncthreads();
        sdata[t] += add;
        __syncthreads();
    }
    if (idx < NN) {
        int excl = sdata[t] - v + bsum[blockIdx.x];
        row_ptr[idx] = excl;
        cursor[idx]  = excl;
        if (idx == NN - 1) row_ptr[NN] = excl + v;
    }
}

// ---------------- fp32 -> bf16 feature conversion ----------------

__global__ __launch_bounds__(256) void f32_to_bf16_kernel(const float* __restrict__ in,
                                                          unsigned int* __restrict__ outb,
                                                          int n8) {
    int i = blockIdx.x * blockDim.x + threadIdx.x;
    if (i >= n8) return;
    const float4* p = (const float4*)in + (size_t)i * 2;
    float4 a = p[0], b = p[1];
    uint4 r;
    r.x = packbf(a.x, a.y);
    r.y = packbf(a.z, a.w);
    r.z = packbf(b.x, b.y);
    r.w = packbf(b.z, b.w);
    ((uint4*)outb)[i] = r;
}

// ---------------- all weights -> MFMA B-fragment layout, one launch ----------------
// frag[(kt*(H/16)+nt)*64 + lane], elem i = W[kt*32 + (lane>>4)*8 + i][nt*16 + (lane&15)]

__device__ __forceinline__ void wfrag_one(const float* __restrict__ W, int H, int idx,
                                          uint4* __restrict__ out) {
    int lane = idx & 63;
    int tile = idx >> 6;
    int ntiles = H >> 4;
    int nt = tile % ntiles;
    int kt = tile / ntiles;
    int kbase = kt * 32 + (lane >> 4) * 8;
    int col = nt * 16 + (lane & 15);
    uint4 r;
    r.x = packbf(W[(size_t)(kbase + 0) * H + col], W[(size_t)(kbase + 1) * H + col]);
    r.y = packbf(W[(size_t)(kbase + 2) * H + col], W[(size_t)(kbase + 3) * H + col]);
    r.z = packbf(W[(size_t)(kbase + 4) * H + col], W[(size_t)(kbase + 5) * H + col]);
    r.w = packbf(W[(size_t)(kbase + 6) * H + col], W[(size_t)(kbase + 7) * H + col]);
    out[idx] = r;
}

__global__ __launch_bounds__(256) void wfrag_all_kernel(
    const float* __restrict__ W1l, const float* __restrict__ W1r,
    const float* __restrict__ W2l, const float* __restrict__ W2r,
    const float* __restrict__ W3l, const float* __restrict__ W3r,
    uint4* __restrict__ wf1, uint4* __restrict__ wf2,
    uint4* __restrict__ wf3l, uint4* __restrict__ wf3r) {
    int idx = blockIdx.x * blockDim.x + threadIdx.x;
    if (idx < 2048)       wfrag_one(W1l, 128, idx, wf1);
    else if (idx < 4096)  wfrag_one(W1r, 128, idx - 2048, wf1 + 2048);
    else if (idx < 6144)  wfrag_one(W2l, 128, idx - 4096, wf2);
    else if (idx < 8192)  wfrag_one(W2r, 128, idx - 6144, wf2 + 2048);
    else if (idx < 9216)  wfrag_one(W3l, 64, idx - 8192, wf3l);
    else if (idx < 10240) wfrag_one(W3r, 64, idx - 9216, wf3r);
}

// ---------------- pull aggregation (mean), bf16 rows, 16 lanes/edge, 4 edges in flight ----------------

__global__ __launch_bounds__(256) void pull_mean128_bf_kernel(
    const uint4* __restrict__ xb4, const int* __restrict__ row_ptr,
    const int* __restrict__ adj, uint4* __restrict__ aggb4) {
    int node = blockIdx.x * 4 + (threadIdx.x >> 6);
    int l = threadIdx.x & 63;
    int g = l >> 4;   // 0..3
    int i = l & 15;   // 16B chunk of the row
    int beg = row_ptr[node], end = row_ptr[node + 1];
    float acc[8];
#pragma unroll
    for (int j = 0; j < 8; ++j) acc[j] = 0.f;

    for (int base = beg; base < end; base += 16) {
        uint4 u[4];
        float m[4];
#pragma unroll
        for (int j = 0; j < 4; ++j) {
            int e = base + j * 4 + g;
            bool v = e < end;
            int s = v ? adj[e] : 0;
            u[j] = xb4[(size_t)s * 16 + i];
            m[j] = v ? 1.f : 0.f;
        }
#pragma unroll
        for (int j = 0; j < 4; ++j) {
            acc[0] = fmaf(m[j], bflo(u[j].x), acc[0]);
            acc[1] = fmaf(m[j], bfhi(u[j].x), acc[1]);
            acc[2] = fmaf(m[j], bflo(u[j].y), acc[2]);
            acc[3] = fmaf(m[j], bfhi(u[j].y), acc[3]);
            acc[4] = fmaf(m[j], bflo(u[j].z), acc[4]);
            acc[5] = fmaf(m[j], bfhi(u[j].z), acc[5]);
            acc[6] = fmaf(m[j], bflo(u[j].w), acc[6]);
            acc[7] = fmaf(m[j], bfhi(u[j].w), acc[7]);
        }
    }

#pragma unroll
    for (int j = 0; j < 8; ++j) {
        acc[j] += __shfl_xor(acc[j], 16);
        acc[j] += __shfl_xor(acc[j], 32);
    }
    if (g == 0) {
        float inv = 1.0f / (float)(end > beg ? (end - beg) : 1);
        uint4 r;
        r.x = packbf(acc[0] * inv, acc[1] * inv);
        r.y = packbf(acc[2] * inv, acc[3] * inv);
        r.z = packbf(acc[4] * inv, acc[5] * inv);
        r.w = packbf(acc[6] * inv, acc[7] * inv);
        aggb4[(size_t)node * 16 + i] = r;
    }
}

__global__ __launch_bounds__(256) void pull_mean64_bf_kernel(
    const uint2* __restrict__ zb2, const int* __restrict__ row_ptr,
    const int* __restrict__ adj, float* __restrict__ aggout) {
    int node = blockIdx.x * 4 + (threadIdx.x >> 6);
    int l = threadIdx.x & 63;
    int g = l >> 4;
    int i = l & 15;
    int beg = row_ptr[node], end = row_ptr[node + 1];
    float acc[4];
#pragma unroll
    for (int j = 0; j < 4; ++j) acc[j] = 0.f;

    for (int base = beg; base < end; base += 16) {
        uint2 u[4];
        float m[4];
#pragma unroll
        for (int j = 0; j < 4; ++j) {
            int e = base + j * 4 + g;
            bool v = e < end;
            int s = v ? adj[e] : 0;
            u[j] = zb2[(size_t)s * 16 + i];
            m[j] = v ? 1.f : 0.f;
        }
#pragma unroll
        for (int j = 0; j < 4; ++j) {
            acc[0] = fmaf(m[j], bflo(u[j].x), acc[0]);
            acc[1] = fmaf(m[j], bfhi(u[j].x), acc[1]);
            acc[2] = fmaf(m[j], bflo(u[j].y), acc[2]);
            acc[3] = fmaf(m[j], bfhi(u[j].y), acc[3]);
        }
    }

#pragma unroll
    for (int j = 0; j < 4; ++j) {
        acc[j] += __shfl_xor(acc[j], 16);
        acc[j] += __shfl_xor(acc[j], 32);
    }
    if (g == 0) {
        float inv = 1.0f / (float)(end > beg ? (end - beg) : 1);
        float4 r;
        r.x = acc[0] * inv;
        r.y = acc[1] * inv;
        r.z = acc[2] * inv;
        r.w = acc[3] * inv;
        *(float4*)(aggout + (size_t)node * 64 + i * 4) = r;
    }
}

// ---------------- MFMA SAGE layer (H=128): out = relu(agg@Wl + xin@Wr + b) ----------------

__global__ __launch_bounds__(256) void sage_mfma_kernel(
    const uint4* __restrict__ aggA, const uint4* __restrict__ xinA,
    const uint4* __restrict__ wfrag, const float* __restrict__ bias,
    unsigned short* __restrict__ outb) {
    const int w = threadIdx.x >> 6;
    const int l = threadIdx.x & 63;
    const int r0 = blockIdx.x * 64 + w * 16;
    int arow = r0 + (l & 15);
    if (arow > NN - 1) arow = NN - 1;
    const int koff = l >> 4;

    f32x4 acc[8];
#pragma unroll
    for (int nt = 0; nt < 8; ++nt) {
        f32x4 z = {0.f, 0.f, 0.f, 0.f};
        acc[nt] = z;
    }

#pragma unroll
    for (int kt = 0; kt < 8; ++kt) {
        const uint4* Ab = (kt < 4) ? aggA : xinA;
        const int ktl = kt & 3;
        bf16x8 av = as_bf8(Ab[(size_t)arow * 16 + ktl * 4 + koff]);
#pragma unroll
        for (int nt = 0; nt < 8; ++nt) {
            bf16x8 bv = as_bf8(wfrag[(kt * 8 + nt) * 64 + l]);
            acc[nt] = __builtin_amdgcn_mfma_f32_16x16x32_bf16(av, bv, acc[nt], 0, 0, 0);
        }
    }

    const int crow0 = r0 + ((l >> 4) << 2);
    const int ccol = l & 15;
#pragma unroll
    for (int nt = 0; nt < 8; ++nt) {
        float bb = bias[nt * 16 + ccol];
#pragma unroll
        for (int i = 0; i < 4; ++i) {
            int r = crow0 + i;
            if (r < NN) {
                float v = fmaxf(acc[nt][i] + bb, 0.f);
                outb[(size_t)r * 128 + nt * 16 + ccol] = f2bf(v);
            }
        }
    }
}

// ---------------- MFMA matmul (K=128 -> H=64) ----------------

template <int MODE>
__global__ __launch_bounds__(256) void mm64_mfma_kernel(
    const uint4* __restrict__ A, const uint4* __restrict__ wfrag,
    const float* __restrict__ addin, const float* __restrict__ bias,
    void* __restrict__ outp) {
    const int w = threadIdx.x >> 6;
    const int l = threadIdx.x & 63;
    const int r0 = blockIdx.x * 64 + w * 16;
    int arow = r0 + (l & 15);
    if (arow > NN - 1) arow = NN - 1;
    const int koff = l >> 4;

    f32x4 acc[4];
#pragma unroll
    for (int nt = 0; nt < 4; ++nt) {
        f32x4 z = {0.f, 0.f, 0.f, 0.f};
        acc[nt] = z;
    }

#pragma unroll
    for (int kt = 0; kt < 4; ++kt) {
        bf16x8 av = as_bf8(A[(size_t)arow * 16 + kt * 4 + koff]);
#pragma unroll
        for (int nt = 0; nt < 4; ++nt) {
            bf16x8 bv = as_bf8(wfrag[(kt * 4 + nt) * 64 + l]);
            acc[nt] = __builtin_amdgcn_mfma_f32_16x16x32_bf16(av, bv, acc[nt], 0, 0, 0);
        }
    }

    const int crow0 = r0 + ((l >> 4) << 2);
    const int ccol = l & 15;
#pragma unroll
    for (int nt = 0; nt < 4; ++nt) {
        int col = nt * 16 + ccol;
#pragma unroll
        for (int i = 0; i < 4; ++i) {
            int r = crow0 + i;
            if (r < NN) {
                if (MODE == 0) {
                    ((unsigned short*)outp)[(size_t)r * 64 + col] = f2bf(acc[nt][i]);
                } else {
                    float v = acc[nt][i] + addin[(size_t)r * 64 + col] + bias[col];
                    ((float*)outp)[(size_t)r * 64 + col] = v;
                }
            }
        }
    }
}

// ---------------- launcher ----------------

extern "C" void kernel_launch(void* const* d_in, const int* in_sizes, int n_in,
                              void* d_out, int out_size, void* d_ws, size_t ws_size,
                              hipStream_t stream) {
    (void)in_sizes; (void)n_in; (void)out_size; (void)ws_size;

    const float* x   = (const float*)d_in[0];
    const int* eidx  = (const int*)d_in[1];
    const int* src   = eidx;
    const int* dst   = eidx + NE;
    const float* W1l = (const float*)d_in[2];
    const float* W1r = (const float*)d_in[3];
    const float* b1  = (const float*)d_in[4];
    const float* W2l = (const float*)d_in[5];
    const float* W2r = (const float*)d_in[6];
    const float* b2  = (const float*)d_in[7];
    const float* W3l = (const float*)d_in[8];
    const float* W3r = (const float*)d_in[9];
    const float* b3  = (const float*)d_in[10];
    float* out = (float*)d_out;

    size_t off = 0;
    auto carve = [&](size_t bytes) -> void* {
        void* p = (char*)d_ws + off;
        off += (bytes + 255) & ~(size_t)255;
        return p;
    };
    int* count   = (int*)carve((size_t)(NN + 64) * 4);  // count[NN] + gcursor[8] tail
    int* gcursor = count + NN;
    int* row_ptr = (int*)carve((size_t)(NN + 1) * 4);
    int* cursor  = (int*)carve((size_t)NN * 4);
    int* bsum    = (int*)carve((size_t)NB_SCAN * 4);
    int* adj     = (int*)carve((size_t)NE * 4);
    uint2* buckets = (uint2*)carve((size_t)8 * CAPB * 8);               // 13.4 MB
    unsigned int* x_bf   = (unsigned int*)carve((size_t)NN * 64 * 4);   // N x 128 bf16
    unsigned int* agg_bf = (unsigned int*)carve((size_t)NN * 64 * 4);
    unsigned int* h1_bf  = (unsigned int*)carve((size_t)NN * 64 * 4);
    unsigned int* h2_bf  = (unsigned int*)carve((size_t)NN * 64 * 4);
    unsigned int* z_bf   = (unsigned int*)carve((size_t)NN * 32 * 4);   // N x 64 bf16
    float* agg3          = (float*)carve((size_t)NN * 64 * 4);          // N x 64 fp32
    uint4* wf1  = (uint4*)carve((size_t)8 * 8 * 64 * 16);
    uint4* wf2  = (uint4*)carve((size_t)8 * 8 * 64 * 16);
    uint4* wf3l = (uint4*)carve((size_t)4 * 4 * 64 * 16);
    uint4* wf3r = (uint4*)carve((size_t)4 * 4 * 64 * 16);

    const int mgrid = (NN + 63) / 64;   // 1563
    const int pgrid = (NN + 3) / 4;     // 25000
    const int cgrid = (NN * 16 + 255) / 256;

    // --- CSR build: bucket -> scan -> local fill ---
    hipMemsetAsync(count, 0, (size_t)(NN + 64) * 4, stream);
    bucket_count_kernel<<<NBLK_BUCKET, 256, 0, stream>>>(src, dst, count, gcursor, buckets);
    block_sum_kernel<<<NB_SCAN, 256, 0, stream>>>(count, bsum);
    scan_bsum_kernel<<<1, 64, 0, stream>>>(bsum, NB_SCAN);
    scan_block_kernel<<<NB_SCAN, 1024, 0, stream>>>(count, bsum, row_ptr, cursor);
    fill_bucket_kernel<<<8 * GBLOCKS, 256, 0, stream>>>(buckets, gcursor, cursor, adj);

    // --- conversions ---
    f32_to_bf16_kernel<<<cgrid, 256, 0, stream>>>(x, x_bf, NN * 16);
    wfrag_all_kernel<<<40, 256, 0, stream>>>(W1l, W1r, W2l, W2r, W3l, W3r, wf1, wf2, wf3l, wf3r);

    // --- layer 1 ---
    pull_mean128_bf_kernel<<<pgrid, 256, 0, stream>>>((const uint4*)x_bf, row_ptr, adj, (uint4*)agg_bf);
    sage_mfma_kernel<<<mgrid, 256, 0, stream>>>((const uint4*)agg_bf, (const uint4*)x_bf,
                                                wf1, b1, (unsigned short*)h1_bf);
    // --- layer 2 ---
    pull_mean128_bf_kernel<<<pgrid, 256, 0, stream>>>((const uint4*)h1_bf, row_ptr, adj, (uint4*)agg_bf);
    sage_mfma_kernel<<<mgrid, 256, 0, stream>>>((const uint4*)agg_bf, (const uint4*)h1_bf,
                                                wf2, b2, (unsigned short*)h2_bf);
    // --- layer 3: z = h2 @ W3l (bf16), pull, out = h2 @ W3r + agg3 + b3 ---
    mm64_mfma_kernel<0><<<mgrid, 256, 0, stream>>>((const uint4*)h2_bf, wf3l, nullptr, nullptr, z_bf);
    pull_mean64_bf_kernel<<<pgrid, 256, 0, stream>>>((const uint2*)z_bf, row_ptr, adj, agg3);
    mm64_mfma_kernel<1><<<mgrid, 256, 0, stream>>>((const uint4*)h2_bf, wf3r, agg3, b3, out);
}

// Round 6
// 340.169 us; speedup vs baseline: 2.7264x; 1.2853x over previous
//
#include <hip/hip_runtime.h>

#define NN 100000
#define NE 1600000
#define NPB 256                    // nodes per bucket
#define NB 391                     // ceil(NN/NPB); 391*256 = 100096
#define CAP 4864                   // bucket capacity (mean 4092, sd 64)
#define NBLK_A 512
#define CHUNK_A (NE / NBLK_A)      // 3125

typedef __attribute__((ext_vector_type(8))) short bf16x8;
typedef __attribute__((ext_vector_type(4))) float f32x4;

// ---------------- bf16 helpers (stored as ushort/uint, math in fp32) ----------------

__device__ __forceinline__ unsigned short f2bf(float f) {
    unsigned int u = __float_as_uint(f);
    unsigned int r = u + 0x7fffu + ((u >> 16) & 1u);  // RNE
    return (unsigned short)(r >> 16);
}
__device__ __forceinline__ float bflo(unsigned int u) { return __uint_as_float(u << 16); }
__device__ __forceinline__ float bfhi(unsigned int u) { return __uint_as_float(u & 0xffff0000u); }
__device__ __forceinline__ unsigned int packbf(float lo, float hi) {
    return ((unsigned int)f2bf(hi) << 16) | (unsigned int)f2bf(lo);
}
__device__ __forceinline__ bf16x8 as_bf8(uint4 u) {
    union { uint4 u; bf16x8 h; } c;
    c.u = u;
    return c.h;
}

// ---------------- CSR build phase A: scatter edges into 391 dst-buckets ----------------
// Per-block LDS histogram (391 bins -> low contention), one global atomic per
// (block,bucket) to reserve space, dense writes. No per-edge global atomics.

__global__ __launch_bounds__(256) void bucket_scatter_kernel(
    const int* __restrict__ src, const int* __restrict__ dst,
    int* __restrict__ gcur, uint2* __restrict__ buckets) {
    __shared__ int hist[NB];
    __shared__ int base[NB];
    int t = threadIdx.x;
    for (int b = t; b < NB; b += 256) hist[b] = 0;
    __syncthreads();
    int e0 = blockIdx.x * CHUNK_A;
    for (int e = e0 + t; e < e0 + CHUNK_A; e += 256)
        atomicAdd(&hist[dst[e] >> 8], 1);
    __syncthreads();
    for (int b = t; b < NB; b += 256) {
        base[b] = atomicAdd(&gcur[b], hist[b]);
        hist[b] = 0;
    }
    __syncthreads();
    for (int e = e0 + t; e < e0 + CHUNK_A; e += 256) {
        int d = dst[e];
        int bkt = d >> 8;
        int slot = base[bkt] + atomicAdd(&hist[bkt], 1);
        if (slot < CAP)  // safety (12-sigma event)
            buckets[(size_t)bkt * CAP + slot] = make_uint2((unsigned)src[e], (unsigned)d);
    }
}

// ---------------- CSR build: tiny serial scan of bucket totals ----------------

__global__ void bucket_scan_kernel(const int* __restrict__ gcur, int* __restrict__ bstart,
                                   int* __restrict__ row_ptr) {
    if (blockIdx.x == 0 && threadIdx.x == 0) {
        int run = 0;
        for (int b = 0; b < NB; ++b) {
            bstart[b] = run;
            run += gcur[b];
        }
        bstart[NB] = run;
        row_ptr[NN] = run;  // == NE (or slightly less if safety clamp ever fired)
    }
}

// ---------------- CSR build phase B: per-bucket finalize (all LDS atomics) ----------------
// One block per bucket: 256-node LDS histogram -> LDS scan -> row_ptr slice,
// then LDS-cursor ranking -> dense adj slice. Zero global atomics.

__global__ __launch_bounds__(256) void csr_finalize_kernel(
    const uint2* __restrict__ buckets, const int* __restrict__ gcur,
    const int* __restrict__ bstart, int* __restrict__ row_ptr, int* __restrict__ adj) {
    __shared__ int hist[NPB];
    __shared__ int scn[NPB];
    int b = blockIdx.x;
    int t = threadIdx.x;
    int n = gcur[b];
    if (n > CAP) n = CAP;
    int base = bstart[b];
    const uint2* bk = buckets + (size_t)b * CAP;

    hist[t] = 0;
    __syncthreads();
    for (int i = t; i < n; i += 256) atomicAdd(&hist[bk[i].y & 255], 1);
    __syncthreads();

    // exclusive scan of 256 ints
    int v = hist[t];
    scn[t] = v;
    __syncthreads();
    for (int off = 1; off < 256; off <<= 1) {
        int add = (t >= off) ? scn[t - off] : 0;
        __syncthreads();
        scn[t] += add;
        __syncthreads();
    }
    int excl = scn[t] - v;
    int node = b * NPB + t;
    if (node < NN) row_ptr[node] = base + excl;

    hist[t] = excl;  // reuse as cursor
    __syncthreads();
    for (int i = t; i < n; i += 256) {
        uint2 pr = bk[i];
        int pos = atomicAdd(&hist[pr.y & 255], 1);
        adj[base + pos] = (int)pr.x;
    }
}

// ---------------- fp32 -> bf16 feature conversion ----------------

__global__ __launch_bounds__(256) void f32_to_bf16_kernel(const float* __restrict__ in,
                                                          unsigned int* __restrict__ outb,
                                                          int n8) {
    int i = blockIdx.x * blockDim.x + threadIdx.x;
    if (i >= n8) return;
    const float4* p = (const float4*)in + (size_t)i * 2;
    float4 a = p[0], b = p[1];
    uint4 r;
    r.x = packbf(a.x, a.y);
    r.y = packbf(a.z, a.w);
    r.z = packbf(b.x, b.y);
    r.w = packbf(b.z, b.w);
    ((uint4*)outb)[i] = r;
}

// ---------------- all weights -> MFMA B-fragment layout, one launch ----------------
// frag[(kt*(H/16)+nt)*64 + lane], elem i = W[kt*32 + (lane>>4)*8 + i][nt*16 + (lane&15)]

__device__ __forceinline__ void wfrag_one(const float* __restrict__ W, int H, int idx,
                                          uint4* __restrict__ out) {
    int lane = idx & 63;
    int tile = idx >> 6;
    int ntiles = H >> 4;
    int nt = tile % ntiles;
    int kt = tile / ntiles;
    int kbase = kt * 32 + (lane >> 4) * 8;
    int col = nt * 16 + (lane & 15);
    uint4 r;
    r.x = packbf(W[(size_t)(kbase + 0) * H + col], W[(size_t)(kbase + 1) * H + col]);
    r.y = packbf(W[(size_t)(kbase + 2) * H + col], W[(size_t)(kbase + 3) * H + col]);
    r.z = packbf(W[(size_t)(kbase + 4) * H + col], W[(size_t)(kbase + 5) * H + col]);
    r.w = packbf(W[(size_t)(kbase + 6) * H + col], W[(size_t)(kbase + 7) * H + col]);
    out[idx] = r;
}

__global__ __launch_bounds__(256) void wfrag_all_kernel(
    const float* __restrict__ W1l, const float* __restrict__ W1r,
    const float* __restrict__ W2l, const float* __restrict__ W2r,
    const float* __restrict__ W3l, const float* __restrict__ W3r,
    uint4* __restrict__ wf1, uint4* __restrict__ wf2,
    uint4* __restrict__ wf3l, uint4* __restrict__ wf3r) {
    int idx = blockIdx.x * blockDim.x + threadIdx.x;
    if (idx < 2048)       wfrag_one(W1l, 128, idx, wf1);
    else if (idx < 4096)  wfrag_one(W1r, 128, idx - 2048, wf1 + 2048);
    else if (idx < 6144)  wfrag_one(W2l, 128, idx - 4096, wf2);
    else if (idx < 8192)  wfrag_one(W2r, 128, idx - 6144, wf2 + 2048);
    else if (idx < 9216)  wfrag_one(W3l, 64, idx - 8192, wf3l);
    else if (idx < 10240) wfrag_one(W3r, 64, idx - 9216, wf3r);
}

// ---------------- pull aggregation (mean), bf16 rows, 16 lanes/edge, 4 edges in flight ----------------

__global__ __launch_bounds__(256) void pull_mean128_bf_kernel(
    const uint4* __restrict__ xb4, const int* __restrict__ row_ptr,
    const int* __restrict__ adj, uint4* __restrict__ aggb4) {
    int node = blockIdx.x * 4 + (threadIdx.x >> 6);
    int l = threadIdx.x & 63;
    int g = l >> 4;   // 0..3
    int i = l & 15;   // 16B chunk of the row
    int beg = row_ptr[node], end = row_ptr[node + 1];
    float acc[8];
#pragma unroll
    for (int j = 0; j < 8; ++j) acc[j] = 0.f;

    for (int base = beg; base < end; base += 16) {
        uint4 u[4];
        float m[4];
#pragma unroll
        for (int j = 0; j < 4; ++j) {
            int e = base + j * 4 + g;
            bool v = e < end;
            int s = v ? adj[e] : 0;
            u[j] = xb4[(size_t)s * 16 + i];
            m[j] = v ? 1.f : 0.f;
        }
#pragma unroll
        for (int j = 0; j < 4; ++j) {
            acc[0] = fmaf(m[j], bflo(u[j].x), acc[0]);
            acc[1] = fmaf(m[j], bfhi(u[j].x), acc[1]);
            acc[2] = fmaf(m[j], bflo(u[j].y), acc[2]);
            acc[3] = fmaf(m[j], bfhi(u[j].y), acc[3]);
            acc[4] = fmaf(m[j], bflo(u[j].z), acc[4]);
            acc[5] = fmaf(m[j], bfhi(u[j].z), acc[5]);
            acc[6] = fmaf(m[j], bflo(u[j].w), acc[6]);
            acc[7] = fmaf(m[j], bfhi(u[j].w), acc[7]);
        }
    }

#pragma unroll
    for (int j = 0; j < 8; ++j) {
        acc[j] += __shfl_xor(acc[j], 16);
        acc[j] += __shfl_xor(acc[j], 32);
    }
    if (g == 0) {
        float inv = 1.0f / (float)(end > beg ? (end - beg) : 1);
        uint4 r;
        r.x = packbf(acc[0] * inv, acc[1] * inv);
        r.y = packbf(acc[2] * inv, acc[3] * inv);
        r.z = packbf(acc[4] * inv, acc[5] * inv);
        r.w = packbf(acc[6] * inv, acc[7] * inv);
        aggb4[(size_t)node * 16 + i] = r;
    }
}

__global__ __launch_bounds__(256) void pull_mean64_bf_kernel(
    const uint2* __restrict__ zb2, const int* __restrict__ row_ptr,
    const int* __restrict__ adj, float* __restrict__ aggout) {
    int node = blockIdx.x * 4 + (threadIdx.x >> 6);
    int l = threadIdx.x & 63;
    int g = l >> 4;
    int i = l & 15;
    int beg = row_ptr[node], end = row_ptr[node + 1];
    float acc[4];
#pragma unroll
    for (int j = 0; j < 4; ++j) acc[j] = 0.f;

    for (int base = beg; base < end; base += 16) {
        uint2 u[4];
        float m[4];
#pragma unroll
        for (int j = 0; j < 4; ++j) {
            int e = base + j * 4 + g;
            bool v = e < end;
            int s = v ? adj[e] : 0;
            u[j] = zb2[(size_t)s * 16 + i];
            m[j] = v ? 1.f : 0.f;
        }
#pragma unroll
        for (int j = 0; j < 4; ++j) {
            acc[0] = fmaf(m[j], bflo(u[j].x), acc[0]);
            acc[1] = fmaf(m[j], bfhi(u[j].x), acc[1]);
            acc[2] = fmaf(m[j], bflo(u[j].y), acc[2]);
            acc[3] = fmaf(m[j], bfhi(u[j].y), acc[3]);
        }
    }

#pragma unroll
    for (int j = 0; j < 4; ++j) {
        acc[j] += __shfl_xor(acc[j], 16);
        acc[j] += __shfl_xor(acc[j], 32);
    }
    if (g == 0) {
        float inv = 1.0f / (float)(end > beg ? (end - beg) : 1);
        float4 r;
        r.x = acc[0] * inv;
        r.y = acc[1] * inv;
        r.z = acc[2] * inv;
        r.w = acc[3] * inv;
        *(float4*)(aggout + (size_t)node * 64 + i * 4) = r;
    }
}

// ---------------- MFMA SAGE layer (H=128): out = relu(agg@Wl + xin@Wr + b) ----------------

__global__ __launch_bounds__(256) void sage_mfma_kernel(
    const uint4* __restrict__ aggA, const uint4* __restrict__ xinA,
    const uint4* __restrict__ wfrag, const float* __restrict__ bias,
    unsigned short* __restrict__ outb) {
    const int w = threadIdx.x >> 6;
    const int l = threadIdx.x & 63;
    const int r0 = blockIdx.x * 64 + w * 16;
    int arow = r0 + (l & 15);
    if (arow > NN - 1) arow = NN - 1;
    const int koff = l >> 4;

    f32x4 acc[8];
#pragma unroll
    for (int nt = 0; nt < 8; ++nt) {
        f32x4 z = {0.f, 0.f, 0.f, 0.f};
        acc[nt] = z;
    }

#pragma unroll
    for (int kt = 0; kt < 8; ++kt) {
        const uint4* Ab = (kt < 4) ? aggA : xinA;
        const int ktl = kt & 3;
        bf16x8 av = as_bf8(Ab[(size_t)arow * 16 + ktl * 4 + koff]);
#pragma unroll
        for (int nt = 0; nt < 8; ++nt) {
            bf16x8 bv = as_bf8(wfrag[(kt * 8 + nt) * 64 + l]);
            acc[nt] = __builtin_amdgcn_mfma_f32_16x16x32_bf16(av, bv, acc[nt], 0, 0, 0);
        }
    }

    const int crow0 = r0 + ((l >> 4) << 2);
    const int ccol = l & 15;
#pragma unroll
    for (int nt = 0; nt < 8; ++nt) {
        float bb = bias[nt * 16 + ccol];
#pragma unroll
        for (int i = 0; i < 4; ++i) {
            int r = crow0 + i;
            if (r < NN) {
                float v = fmaxf(acc[nt][i] + bb, 0.f);
                outb[(size_t)r * 128 + nt * 16 + ccol] = f2bf(v);
            }
        }
    }
}

// ---------------- MFMA matmul (K=128 -> H=64) ----------------

template <int MODE>
__global__ __launch_bounds__(256) void mm64_mfma_kernel(
    const uint4* __restrict__ A, const uint4* __restrict__ wfrag,
    const float* __restrict__ addin, const float* __restrict__ bias,
    void* __restrict__ outp) {
    const int w = threadIdx.x >> 6;
    const int l = threadIdx.x & 63;
    const int r0 = blockIdx.x * 64 + w * 16;
    int arow = r0 + (l & 15);
    if (arow > NN - 1) arow = NN - 1;
    const int koff = l >> 4;

    f32x4 acc[4];
#pragma unroll
    for (int nt = 0; nt < 4; ++nt) {
        f32x4 z = {0.f, 0.f, 0.f, 0.f};
        acc[nt] = z;
    }

#pragma unroll
    for (int kt = 0; kt < 4; ++kt) {
        bf16x8 av = as_bf8(A[(size_t)arow * 16 + kt * 4 + koff]);
#pragma unroll
        for (int nt = 0; nt < 4; ++nt) {
            bf16x8 bv = as_bf8(wfrag[(kt * 4 + nt) * 64 + l]);
            acc[nt] = __builtin_amdgcn_mfma_f32_16x16x32_bf16(av, bv, acc[nt], 0, 0, 0);
        }
    }

    const int crow0 = r0 + ((l >> 4) << 2);
    const int ccol = l & 15;
#pragma unroll
    for (int nt = 0; nt < 4; ++nt) {
        int col = nt * 16 + ccol;
#pragma unroll
        for (int i = 0; i < 4; ++i) {
            int r = crow0 + i;
            if (r < NN) {
                if (MODE == 0) {
                    ((unsigned short*)outp)[(size_t)r * 64 + col] = f2bf(acc[nt][i]);
                } else {
                    float v = acc[nt][i] + addin[(size_t)r * 64 + col] + bias[col];
                    ((float*)outp)[(size_t)r * 64 + col] = v;
                }
            }
        }
    }
}

// ---------------- launcher ----------------

extern "C" void kernel_launch(void* const* d_in, const int* in_sizes, int n_in,
                              void* d_out, int out_size, void* d_ws, size_t ws_size,
                              hipStream_t stream) {
    (void)in_sizes; (void)n_in; (void)out_size; (void)ws_size;

    const float* x   = (const float*)d_in[0];
    const int* eidx  = (const int*)d_in[1];
    const int* src   = eidx;
    const int* dst   = eidx + NE;
    const float* W1l = (const float*)d_in[2];
    const float* W1r = (const float*)d_in[3];
    const float* b1  = (const float*)d_in[4];
    const float* W2l = (const float*)d_in[5];
    const float* W2r = (const float*)d_in[6];
    const float* b2  = (const float*)d_in[7];
    const float* W3l = (const float*)d_in[8];
    const float* W3r = (const float*)d_in[9];
    const float* b3  = (const float*)d_in[10];
    float* out = (float*)d_out;

    size_t off = 0;
    auto carve = [&](size_t bytes) -> void* {
        void* p = (char*)d_ws + off;
        off += (bytes + 255) & ~(size_t)255;
        return p;
    };
    int* gcur    = (int*)carve((size_t)NB * 4);
    int* bstart  = (int*)carve((size_t)(NB + 1) * 4);
    int* row_ptr = (int*)carve((size_t)(NN + 1) * 4);
    int* adj     = (int*)carve((size_t)NE * 4);
    uint2* buckets = (uint2*)carve((size_t)NB * CAP * 8);               // 15.2 MB
    unsigned int* x_bf   = (unsigned int*)carve((size_t)NN * 64 * 4);   // N x 128 bf16
    unsigned int* agg_bf = (unsigned int*)carve((size_t)NN * 64 * 4);
    unsigned int* h1_bf  = (unsigned int*)carve((size_t)NN * 64 * 4);
    unsigned int* h2_bf  = (unsigned int*)carve((size_t)NN * 64 * 4);
    unsigned int* z_bf   = (unsigned int*)carve((size_t)NN * 32 * 4);   // N x 64 bf16
    float* agg3          = (float*)carve((size_t)NN * 64 * 4);          // N x 64 fp32
    uint4* wf1  = (uint4*)carve((size_t)8 * 8 * 64 * 16);
    uint4* wf2  = (uint4*)carve((size_t)8 * 8 * 64 * 16);
    uint4* wf3l = (uint4*)carve((size_t)4 * 4 * 64 * 16);
    uint4* wf3r = (uint4*)carve((size_t)4 * 4 * 64 * 16);

    const int mgrid = (NN + 63) / 64;   // 1563
    const int pgrid = (NN + 3) / 4;     // 25000
    const int cgrid = (NN * 16 + 255) / 256;

    // --- CSR build: scatter -> scan -> per-bucket finalize (no per-edge global atomics) ---
    hipMemsetAsync(gcur, 0, (size_t)NB * 4, stream);
    bucket_scatter_kernel<<<NBLK_A, 256, 0, stream>>>(src, dst, gcur, buckets);
    bucket_scan_kernel<<<1, 64, 0, stream>>>(gcur, bstart, row_ptr);
    csr_finalize_kernel<<<NB, 256, 0, stream>>>(buckets, gcur, bstart, row_ptr, adj);

    // --- conversions ---
    f32_to_bf16_kernel<<<cgrid, 256, 0, stream>>>(x, x_bf, NN * 16);
    wfrag_all_kernel<<<40, 256, 0, stream>>>(W1l, W1r, W2l, W2r, W3l, W3r, wf1, wf2, wf3l, wf3r);

    // --- layer 1 ---
    pull_mean128_bf_kernel<<<pgrid, 256, 0, stream>>>((const uint4*)x_bf, row_ptr, adj, (uint4*)agg_bf);
    sage_mfma_kernel<<<mgrid, 256, 0, stream>>>((const uint4*)agg_bf, (const uint4*)x_bf,
                                                wf1, b1, (unsigned short*)h1_bf);
    // --- layer 2 ---
    pull_mean128_bf_kernel<<<pgrid, 256, 0, stream>>>((const uint4*)h1_bf, row_ptr, adj, (uint4*)agg_bf);
    sage_mfma_kernel<<<mgrid, 256, 0, stream>>>((const uint4*)agg_bf, (const uint4*)h1_bf,
                                                wf2, b2, (unsigned short*)h2_bf);
    // --- layer 3: z = h2 @ W3l (bf16), pull, out = h2 @ W3r + agg3 + b3 ---
    mm64_mfma_kernel<0><<<mgrid, 256, 0, stream>>>((const uint4*)h2_bf, wf3l, nullptr, nullptr, z_bf);
    pull_mean64_bf_kernel<<<pgrid, 256, 0, stream>>>((const uint2*)z_bf, row_ptr, adj, agg3);
    mm64_mfma_kernel<1><<<mgrid, 256, 0, stream>>>((const uint4*)h2_bf, wf3r, agg3, b3, out);
}

// Round 7
// 333.502 us; speedup vs baseline: 2.7809x; 1.0200x over previous
//
#include <hip/hip_runtime.h>

#define NN 100000
#define NE 1600000
#define NPB 256                    // nodes per bucket
#define NB 391                     // ceil(NN/NPB)
#define CAP 4864                   // bucket capacity (mean 4092, sd 64)
#define NBLK_A 512
#define CHUNK_A (NE / NBLK_A)      // 3125
#define CVT_N (NN * 16)            // 1.6M cvt threads (8 floats each)

typedef __attribute__((ext_vector_type(8))) short bf16x8;
typedef __attribute__((ext_vector_type(4))) float f32x4;

// ---------------- bf16 helpers (stored as ushort/uint, math in fp32) ----------------

__device__ __forceinline__ unsigned short f2bf(float f) {
    unsigned int u = __float_as_uint(f);
    unsigned int r = u + 0x7fffu + ((u >> 16) & 1u);  // RNE
    return (unsigned short)(r >> 16);
}
__device__ __forceinline__ float bflo(unsigned int u) { return __uint_as_float(u << 16); }
__device__ __forceinline__ float bfhi(unsigned int u) { return __uint_as_float(u & 0xffff0000u); }
__device__ __forceinline__ unsigned int packbf(float lo, float hi) {
    return ((unsigned int)f2bf(hi) << 16) | (unsigned int)f2bf(lo);
}
__device__ __forceinline__ bf16x8 as_bf8(uint4 u) {
    union { uint4 u; bf16x8 h; } c;
    c.u = u;
    return c.h;
}

// ---------------- CSR build phase A: scatter edges into 391 dst-buckets ----------------
// Packed entry: (d & 255) << 24 | src   (src < 2^17). Halves bucket traffic.

__global__ __launch_bounds__(256) void bucket_scatter_kernel(
    const int* __restrict__ src, const int* __restrict__ dst,
    int* __restrict__ gcur, unsigned* __restrict__ buckets) {
    __shared__ int hist[NB];
    __shared__ int base[NB];
    int t = threadIdx.x;
    for (int b = t; b < NB; b += 256) hist[b] = 0;
    __syncthreads();
    int e0 = blockIdx.x * CHUNK_A;
    for (int e = e0 + t; e < e0 + CHUNK_A; e += 256)
        atomicAdd(&hist[dst[e] >> 8], 1);
    __syncthreads();
    for (int b = t; b < NB; b += 256) {
        base[b] = atomicAdd(&gcur[b], hist[b]);
        hist[b] = 0;
    }
    __syncthreads();
    for (int e = e0 + t; e < e0 + CHUNK_A; e += 256) {
        int d = dst[e];
        int bkt = d >> 8;
        int slot = base[bkt] + atomicAdd(&hist[bkt], 1);
        if (slot < CAP)  // safety (12-sigma event)
            buckets[(size_t)bkt * CAP + slot] =
                ((unsigned)(d & 255) << 24) | (unsigned)src[e];
    }
}

// ---------------- CSR build: parallel scan of bucket totals (1 block) ----------------

__global__ __launch_bounds__(512) void bucket_scan_kernel(
    const int* __restrict__ gcur, int* __restrict__ bstart, int* __restrict__ row_ptr) {
    __shared__ int s[512];
    int t = threadIdx.x;
    int v = (t < NB) ? gcur[t] : 0;
    s[t] = v;
    __syncthreads();
    for (int off = 1; off < 512; off <<= 1) {
        int a = (t >= off) ? s[t - off] : 0;
        __syncthreads();
        s[t] += a;
        __syncthreads();
    }
    if (t < NB) bstart[t] = s[t] - v;
    if (t == NB - 1) {
        bstart[NB] = s[t];
        row_ptr[NN] = s[t];
    }
}

// ---------------- CSR build phase B: per-bucket finalize (all LDS atomics) ----------------

__global__ __launch_bounds__(256) void csr_finalize_kernel(
    const unsigned* __restrict__ buckets, const int* __restrict__ gcur,
    const int* __restrict__ bstart, int* __restrict__ row_ptr, int* __restrict__ adj) {
    __shared__ int hist[NPB];
    __shared__ int scn[NPB];
    int b = blockIdx.x;
    int t = threadIdx.x;
    int n = gcur[b];
    if (n > CAP) n = CAP;
    int base = bstart[b];
    const unsigned* bk = buckets + (size_t)b * CAP;

    hist[t] = 0;
    __syncthreads();
    for (int i = t; i < n; i += 256) atomicAdd(&hist[bk[i] >> 24], 1);
    __syncthreads();

    int v = hist[t];
    scn[t] = v;
    __syncthreads();
    for (int off = 1; off < 256; off <<= 1) {
        int add = (t >= off) ? scn[t - off] : 0;
        __syncthreads();
        scn[t] += add;
        __syncthreads();
    }
    int excl = scn[t] - v;
    int node = b * NPB + t;
    if (node < NN) row_ptr[node] = base + excl;

    hist[t] = excl;  // reuse as cursor
    __syncthreads();
    for (int i = t; i < n; i += 256) {
        unsigned pr = bk[i];
        int pos = atomicAdd(&hist[pr >> 24], 1);
        adj[base + pos] = (int)(pr & 0xFFFFFFu);
    }
}

// ---------------- prep: x -> bf16 AND all weights -> MFMA frag layout ----------------
// frag[(kt*(H/16)+nt)*64 + lane], elem i = W[kt*32 + (lane>>4)*8 + i][nt*16 + (lane&15)]

__device__ __forceinline__ void wfrag_one(const float* __restrict__ W, int H, int idx,
                                          uint4* __restrict__ out) {
    int lane = idx & 63;
    int tile = idx >> 6;
    int ntiles = H >> 4;
    int nt = tile % ntiles;
    int kt = tile / ntiles;
    int kbase = kt * 32 + (lane >> 4) * 8;
    int col = nt * 16 + (lane & 15);
    uint4 r;
    r.x = packbf(W[(size_t)(kbase + 0) * H + col], W[(size_t)(kbase + 1) * H + col]);
    r.y = packbf(W[(size_t)(kbase + 2) * H + col], W[(size_t)(kbase + 3) * H + col]);
    r.z = packbf(W[(size_t)(kbase + 4) * H + col], W[(size_t)(kbase + 5) * H + col]);
    r.w = packbf(W[(size_t)(kbase + 6) * H + col], W[(size_t)(kbase + 7) * H + col]);
    out[idx] = r;
}

__global__ __launch_bounds__(256) void prep_kernel(
    const float* __restrict__ x, unsigned int* __restrict__ x_bf,
    const float* __restrict__ W1l, const float* __restrict__ W1r,
    const float* __restrict__ W2l, const float* __restrict__ W2r,
    const float* __restrict__ W3l, const float* __restrict__ W3r,
    uint4* __restrict__ wf1, uint4* __restrict__ wf2,
    uint4* __restrict__ wf3l, uint4* __restrict__ wf3r) {
    int idx = blockIdx.x * blockDim.x + threadIdx.x;
    if (idx < CVT_N) {
        const float4* p = (const float4*)x + (size_t)idx * 2;
        float4 a = p[0], b = p[1];
        uint4 r;
        r.x = packbf(a.x, a.y);
        r.y = packbf(a.z, a.w);
        r.z = packbf(b.x, b.y);
        r.w = packbf(b.z, b.w);
        ((uint4*)x_bf)[idx] = r;
    } else {
        int k = idx - CVT_N;
        if (k < 2048)       wfrag_one(W1l, 128, k, wf1);
        else if (k < 4096)  wfrag_one(W1r, 128, k - 2048, wf1 + 2048);
        else if (k < 6144)  wfrag_one(W2l, 128, k - 4096, wf2);
        else if (k < 8192)  wfrag_one(W2r, 128, k - 6144, wf2 + 2048);
        else if (k < 9216)  wfrag_one(W3l, 64, k - 8192, wf3l);
        else if (k < 10240) wfrag_one(W3r, 64, k - 9216, wf3r);
    }
}

// ---------------- fused layer: pull_mean128 -> LDS -> MFMA GEMM -> relu -> bf16 out ----------------
// Block = 4 waves, 64 nodes; wave w owns nodes [blk*64 + w*16, +16).
// Phase 1 (per wave): pull each node's mean into LDS (bf16-packed, wave-local, no barrier).
// Phase 2 (per wave): A-frags kt 0..3 from LDS (agg), kt 4..7 from global (xin).

__global__ __launch_bounds__(256) void sage_fused_kernel(
    const uint4* __restrict__ xb4, const int* __restrict__ row_ptr,
    const int* __restrict__ adj, const uint4* __restrict__ wfrag,
    const float* __restrict__ bias, unsigned short* __restrict__ outb) {
    __shared__ uint4 As[64][17];  // +1 uint4 pad to spread banks

    const int w = threadIdx.x >> 6;
    const int l = threadIdx.x & 63;
    const int g = l >> 4;   // edge-group 0..3
    const int i = l & 15;   // 16B chunk of row
    const int r0 = blockIdx.x * 64 + w * 16;

    // ---- phase 1: pull 16 node means ----
    for (int wnode = 0; wnode < 16; ++wnode) {
        int node = r0 + wnode;
        float acc[8];
#pragma unroll
        for (int j = 0; j < 8; ++j) acc[j] = 0.f;
        int beg = 0, end = 0;
        if (node < NN) {
            beg = row_ptr[node];
            end = row_ptr[node + 1];
        }
        int p = beg;
        // unmasked full iterations (16 edges each)
        for (; p + 16 <= end; p += 16) {
#pragma unroll
            for (int j = 0; j < 4; ++j) {
                int s = adj[p + j * 4 + g];
                uint4 u = xb4[(size_t)s * 16 + i];
                acc[0] += bflo(u.x);
                acc[1] += bfhi(u.x);
                acc[2] += bflo(u.y);
                acc[3] += bfhi(u.y);
                acc[4] += bflo(u.z);
                acc[5] += bfhi(u.z);
                acc[6] += bflo(u.w);
                acc[7] += bfhi(u.w);
            }
        }
        // masked tail
        if (p < end) {
#pragma unroll
            for (int j = 0; j < 4; ++j) {
                int e = p + j * 4 + g;
                bool vv = e < end;
                int s = vv ? adj[e] : 0;
                uint4 u = xb4[(size_t)s * 16 + i];
                float m = vv ? 1.f : 0.f;
                acc[0] = fmaf(m, bflo(u.x), acc[0]);
                acc[1] = fmaf(m, bfhi(u.x), acc[1]);
                acc[2] = fmaf(m, bflo(u.y), acc[2]);
                acc[3] = fmaf(m, bfhi(u.y), acc[3]);
                acc[4] = fmaf(m, bflo(u.z), acc[4]);
                acc[5] = fmaf(m, bfhi(u.z), acc[5]);
                acc[6] = fmaf(m, bflo(u.w), acc[6]);
                acc[7] = fmaf(m, bfhi(u.w), acc[7]);
            }
        }
#pragma unroll
        for (int j = 0; j < 8; ++j) {
            acc[j] += __shfl_xor(acc[j], 16);
            acc[j] += __shfl_xor(acc[j], 32);
        }
        if (g == 0) {
            float inv = 1.0f / (float)(end > beg ? (end - beg) : 1);
            uint4 r;
            r.x = packbf(acc[0] * inv, acc[1] * inv);
            r.y = packbf(acc[2] * inv, acc[3] * inv);
            r.z = packbf(acc[4] * inv, acc[5] * inv);
            r.w = packbf(acc[6] * inv, acc[7] * inv);
            As[w * 16 + wnode][i] = r;
        }
    }

    // ---- phase 2: GEMM (wave-local LDS agg + global xin) ----
    const int koff = g;
    int arow = r0 + (l & 15);
    if (arow > NN - 1) arow = NN - 1;

    f32x4 acc[8];
#pragma unroll
    for (int nt = 0; nt < 8; ++nt) {
        f32x4 z = {0.f, 0.f, 0.f, 0.f};
        acc[nt] = z;
    }

#pragma unroll
    for (int kt = 0; kt < 4; ++kt) {  // agg half from LDS
        bf16x8 av = as_bf8(As[w * 16 + (l & 15)][kt * 4 + koff]);
#pragma unroll
        for (int nt = 0; nt < 8; ++nt) {
            bf16x8 bv = as_bf8(wfrag[(kt * 8 + nt) * 64 + l]);
            acc[nt] = __builtin_amdgcn_mfma_f32_16x16x32_bf16(av, bv, acc[nt], 0, 0, 0);
        }
    }
#pragma unroll
    for (int kt = 4; kt < 8; ++kt) {  // xin half from global
        bf16x8 av = as_bf8(xb4[(size_t)arow * 16 + (kt & 3) * 4 + koff]);
#pragma unroll
        for (int nt = 0; nt < 8; ++nt) {
            bf16x8 bv = as_bf8(wfrag[(kt * 8 + nt) * 64 + l]);
            acc[nt] = __builtin_amdgcn_mfma_f32_16x16x32_bf16(av, bv, acc[nt], 0, 0, 0);
        }
    }

    const int crow0 = r0 + ((l >> 4) << 2);
    const int ccol = l & 15;
#pragma unroll
    for (int nt = 0; nt < 8; ++nt) {
        float bb = bias[nt * 16 + ccol];
#pragma unroll
        for (int q = 0; q < 4; ++q) {
            int r = crow0 + q;
            if (r < NN) {
                float v = fmaxf(acc[nt][q] + bb, 0.f);
                outb[(size_t)r * 128 + nt * 16 + ccol] = f2bf(v);
            }
        }
    }
}

// ---------------- MFMA matmul z = h2 @ W3l (K=128 -> H=64), bf16 out ----------------

__global__ __launch_bounds__(256) void mm64_mfma_kernel(
    const uint4* __restrict__ A, const uint4* __restrict__ wfrag,
    unsigned short* __restrict__ outb) {
    const int w = threadIdx.x >> 6;
    const int l = threadIdx.x & 63;
    const int r0 = blockIdx.x * 64 + w * 16;
    int arow = r0 + (l & 15);
    if (arow > NN - 1) arow = NN - 1;
    const int koff = l >> 4;

    f32x4 acc[4];
#pragma unroll
    for (int nt = 0; nt < 4; ++nt) {
        f32x4 z = {0.f, 0.f, 0.f, 0.f};
        acc[nt] = z;
    }

#pragma unroll
    for (int kt = 0; kt < 4; ++kt) {
        bf16x8 av = as_bf8(A[(size_t)arow * 16 + kt * 4 + koff]);
#pragma unroll
        for (int nt = 0; nt < 4; ++nt) {
            bf16x8 bv = as_bf8(wfrag[(kt * 4 + nt) * 64 + l]);
            acc[nt] = __builtin_amdgcn_mfma_f32_16x16x32_bf16(av, bv, acc[nt], 0, 0, 0);
        }
    }

    const int crow0 = r0 + ((l >> 4) << 2);
    const int ccol = l & 15;
#pragma unroll
    for (int nt = 0; nt < 4; ++nt) {
        int col = nt * 16 + ccol;
#pragma unroll
        for (int q = 0; q < 4; ++q) {
            int r = crow0 + q;
            if (r < NN) outb[(size_t)r * 64 + col] = f2bf(acc[nt][q]);
        }
    }
}

// ---------------- fused final: pull_mean64(z) -> LDS, out = h2@W3r + agg + b3 (fp32) ----------------

__global__ __launch_bounds__(256) void final_fused_kernel(
    const uint2* __restrict__ zb2, const int* __restrict__ row_ptr,
    const int* __restrict__ adj, const uint4* __restrict__ h2A,
    const uint4* __restrict__ wfrag, const float* __restrict__ bias,
    float* __restrict__ out) {
    __shared__ float As64[64][68];  // +4 f32 pad

    const int w = threadIdx.x >> 6;
    const int l = threadIdx.x & 63;
    const int g = l >> 4;
    const int i = l & 15;
    const int r0 = blockIdx.x * 64 + w * 16;

    // ---- phase 1: pull 16 node means of z (64-wide) ----
    for (int wnode = 0; wnode < 16; ++wnode) {
        int node = r0 + wnode;
        float acc[4];
#pragma unroll
        for (int j = 0; j < 4; ++j) acc[j] = 0.f;
        int beg = 0, end = 0;
        if (node < NN) {
            beg = row_ptr[node];
            end = row_ptr[node + 1];
        }
        int p = beg;
        for (; p + 16 <= end; p += 16) {
#pragma unroll
            for (int j = 0; j < 4; ++j) {
                int s = adj[p + j * 4 + g];
                uint2 u = zb2[(size_t)s * 16 + i];
                acc[0] += bflo(u.x);
                acc[1] += bfhi(u.x);
                acc[2] += bflo(u.y);
                acc[3] += bfhi(u.y);
            }
        }
        if (p < end) {
#pragma unroll
            for (int j = 0; j < 4; ++j) {
                int e = p + j * 4 + g;
                bool vv = e < end;
                int s = vv ? adj[e] : 0;
                uint2 u = zb2[(size_t)s * 16 + i];
                float m = vv ? 1.f : 0.f;
                acc[0] = fmaf(m, bflo(u.x), acc[0]);
                acc[1] = fmaf(m, bfhi(u.x), acc[1]);
                acc[2] = fmaf(m, bflo(u.y), acc[2]);
                acc[3] = fmaf(m, bfhi(u.y), acc[3]);
            }
        }
#pragma unroll
        for (int j = 0; j < 4; ++j) {
            acc[j] += __shfl_xor(acc[j], 16);
            acc[j] += __shfl_xor(acc[j], 32);
        }
        if (g == 0) {
            float inv = 1.0f / (float)(end > beg ? (end - beg) : 1);
            float4 r;
            r.x = acc[0] * inv;
            r.y = acc[1] * inv;
            r.z = acc[2] * inv;
            r.w = acc[3] * inv;
            *(float4*)(&As64[w * 16 + wnode][i * 4]) = r;
        }
    }

    // ---- phase 2: out = h2 @ W3r + agg + bias ----
    int arow = r0 + (l & 15);
    if (arow > NN - 1) arow = NN - 1;
    const int koff = g;

    f32x4 acc[4];
#pragma unroll
    for (int nt = 0; nt < 4; ++nt) {
        f32x4 z = {0.f, 0.f, 0.f, 0.f};
        acc[nt] = z;
    }

#pragma unroll
    for (int kt = 0; kt < 4; ++kt) {
        bf16x8 av = as_bf8(h2A[(size_t)arow * 16 + kt * 4 + koff]);
#pragma unroll
        for (int nt = 0; nt < 4; ++nt) {
            bf16x8 bv = as_bf8(wfrag[(kt * 4 + nt) * 64 + l]);
            acc[nt] = __builtin_amdgcn_mfma_f32_16x16x32_bf16(av, bv, acc[nt], 0, 0, 0);
        }
    }

    const int lrow0 = (l >> 4) << 2;
    const int ccol = l & 15;
#pragma unroll
    for (int nt = 0; nt < 4; ++nt) {
        int col = nt * 16 + ccol;
        float bb = bias[col];
#pragma unroll
        for (int q = 0; q < 4; ++q) {
            int r = r0 + lrow0 + q;
            if (r < NN) {
                float v = acc[nt][q] + As64[w * 16 + lrow0 + q][col] + bb;
                out[(size_t)r * 64 + col] = v;
            }
        }
    }
}

// ---------------- launcher ----------------

extern "C" void kernel_launch(void* const* d_in, const int* in_sizes, int n_in,
                              void* d_out, int out_size, void* d_ws, size_t ws_size,
                              hipStream_t stream) {
    (void)in_sizes; (void)n_in; (void)out_size; (void)ws_size;

    const float* x   = (const float*)d_in[0];
    const int* eidx  = (const int*)d_in[1];
    const int* src   = eidx;
    const int* dst   = eidx + NE;
    const float* W1l = (const float*)d_in[2];
    const float* W1r = (const float*)d_in[3];
    const float* b1  = (const float*)d_in[4];
    const float* W2l = (const float*)d_in[5];
    const float* W2r = (const float*)d_in[6];
    const float* b2  = (const float*)d_in[7];
    const float* W3l = (const float*)d_in[8];
    const float* W3r = (const float*)d_in[9];
    const float* b3  = (const float*)d_in[10];
    float* out = (float*)d_out;

    size_t off = 0;
    auto carve = [&](size_t bytes) -> void* {
        void* p = (char*)d_ws + off;
        off += (bytes + 255) & ~(size_t)255;
        return p;
    };
    int* gcur    = (int*)carve((size_t)NB * 4);
    int* bstart  = (int*)carve((size_t)(NB + 1) * 4);
    int* row_ptr = (int*)carve((size_t)(NN + 1) * 4);
    int* adj     = (int*)carve((size_t)NE * 4);
    unsigned* buckets = (unsigned*)carve((size_t)NB * CAP * 4);         // 7.6 MB
    unsigned int* x_bf  = (unsigned int*)carve((size_t)NN * 64 * 4);    // N x 128 bf16
    unsigned int* h1_bf = (unsigned int*)carve((size_t)NN * 64 * 4);
    unsigned int* h2_bf = (unsigned int*)carve((size_t)NN * 64 * 4);
    unsigned int* z_bf  = (unsigned int*)carve((size_t)NN * 32 * 4);    // N x 64 bf16
    uint4* wf1  = (uint4*)carve((size_t)8 * 8 * 64 * 16);
    uint4* wf2  = (uint4*)carve((size_t)8 * 8 * 64 * 16);
    uint4* wf3l = (uint4*)carve((size_t)4 * 4 * 64 * 16);
    uint4* wf3r = (uint4*)carve((size_t)4 * 4 * 64 * 16);

    const int mgrid = (NN + 63) / 64;                       // 1563
    const int pgrid = (CVT_N + 10240 + 255) / 256;          // 6290

    // --- CSR build: scatter -> scan -> per-bucket finalize ---
    hipMemsetAsync(gcur, 0, (size_t)NB * 4, stream);
    bucket_scatter_kernel<<<NBLK_A, 256, 0, stream>>>(src, dst, gcur, buckets);
    bucket_scan_kernel<<<1, 512, 0, stream>>>(gcur, bstart, row_ptr);
    csr_finalize_kernel<<<NB, 256, 0, stream>>>(buckets, gcur, bstart, row_ptr, adj);

    // --- prep: x cvt + weight frags (one launch) ---
    prep_kernel<<<pgrid, 256, 0, stream>>>(x, x_bf, W1l, W1r, W2l, W2r, W3l, W3r,
                                           wf1, wf2, wf3l, wf3r);

    // --- layer 1 (fused pull + GEMM) ---
    sage_fused_kernel<<<mgrid, 256, 0, stream>>>((const uint4*)x_bf, row_ptr, adj,
                                                 wf1, b1, (unsigned short*)h1_bf);
    // --- layer 2 ---
    sage_fused_kernel<<<mgrid, 256, 0, stream>>>((const uint4*)h1_bf, row_ptr, adj,
                                                 wf2, b2, (unsigned short*)h2_bf);
    // --- layer 3 ---
    mm64_mfma_kernel<<<mgrid, 256, 0, stream>>>((const uint4*)h2_bf, wf3l,
                                                (unsigned short*)z_bf);
    final_fused_kernel<<<mgrid, 256, 0, stream>>>((const uint2*)z_bf, row_ptr, adj,
                                                  (const uint4*)h2_bf, wf3r, b3, out);
}

// Round 8
// 329.738 us; speedup vs baseline: 2.8126x; 1.0114x over previous
//
#include <hip/hip_runtime.h>

#define NN 100000
#define NE 1600000
#define NPB 256                    // nodes per bucket
#define NB 391                     // ceil(NN/NPB)
#define CAP 4864                   // bucket capacity (mean 4092, sd 64)
#define NBLK_A 512
#define CHUNK_A (NE / NBLK_A)      // 3125
#define CVT_N (NN * 16)            // 1.6M cvt threads (8 floats each)

typedef __attribute__((ext_vector_type(8))) short bf16x8;
typedef __attribute__((ext_vector_type(4))) float f32x4;

// ---------------- bf16 helpers (stored as ushort/uint, math in fp32) ----------------

__device__ __forceinline__ unsigned short f2bf(float f) {
    unsigned int u = __float_as_uint(f);
    unsigned int r = u + 0x7fffu + ((u >> 16) & 1u);  // RNE
    return (unsigned short)(r >> 16);
}
__device__ __forceinline__ float bflo(unsigned int u) { return __uint_as_float(u << 16); }
__device__ __forceinline__ float bfhi(unsigned int u) { return __uint_as_float(u & 0xffff0000u); }
__device__ __forceinline__ unsigned int packbf(float lo, float hi) {
    return ((unsigned int)f2bf(hi) << 16) | (unsigned int)f2bf(lo);
}
__device__ __forceinline__ bf16x8 as_bf8(uint4 u) {
    union { uint4 u; bf16x8 h; } c;
    c.u = u;
    return c.h;
}

// ---------------- CSR build phase A: scatter edges into 391 dst-buckets ----------------
// Packed entry: (d & 255) << 24 | src   (src < 2^17).

__global__ __launch_bounds__(256) void bucket_scatter_kernel(
    const int* __restrict__ src, const int* __restrict__ dst,
    int* __restrict__ gcur, unsigned* __restrict__ buckets) {
    __shared__ int hist[NB];
    __shared__ int base[NB];
    int t = threadIdx.x;
    for (int b = t; b < NB; b += 256) hist[b] = 0;
    __syncthreads();
    int e0 = blockIdx.x * CHUNK_A;
    for (int e = e0 + t; e < e0 + CHUNK_A; e += 256)
        atomicAdd(&hist[dst[e] >> 8], 1);
    __syncthreads();
    for (int b = t; b < NB; b += 256) {
        base[b] = atomicAdd(&gcur[b], hist[b]);
        hist[b] = 0;
    }
    __syncthreads();
    for (int e = e0 + t; e < e0 + CHUNK_A; e += 256) {
        int d = dst[e];
        int bkt = d >> 8;
        int slot = base[bkt] + atomicAdd(&hist[bkt], 1);
        if (slot < CAP)  // safety (12-sigma event)
            buckets[(size_t)bkt * CAP + slot] =
                ((unsigned)(d & 255) << 24) | (unsigned)src[e];
    }
}

// ---------------- CSR build: parallel scan of bucket totals (1 block) ----------------

__global__ __launch_bounds__(512) void bucket_scan_kernel(
    const int* __restrict__ gcur, int* __restrict__ bstart, int* __restrict__ row_ptr) {
    __shared__ int s[512];
    int t = threadIdx.x;
    int v = (t < NB) ? gcur[t] : 0;
    s[t] = v;
    __syncthreads();
    for (int off = 1; off < 512; off <<= 1) {
        int a = (t >= off) ? s[t - off] : 0;
        __syncthreads();
        s[t] += a;
        __syncthreads();
    }
    if (t < NB) bstart[t] = s[t] - v;
    if (t == NB - 1) {
        bstart[NB] = s[t];
        row_ptr[NN] = s[t];
    }
}

// ---------------- CSR build phase B: per-bucket finalize (all LDS atomics) ----------------

__global__ __launch_bounds__(256) void csr_finalize_kernel(
    const unsigned* __restrict__ buckets, const int* __restrict__ gcur,
    const int* __restrict__ bstart, int* __restrict__ row_ptr, int* __restrict__ adj) {
    __shared__ int hist[NPB];
    __shared__ int scn[NPB];
    int b = blockIdx.x;
    int t = threadIdx.x;
    int n = gcur[b];
    if (n > CAP) n = CAP;
    int base = bstart[b];
    const unsigned* bk = buckets + (size_t)b * CAP;

    hist[t] = 0;
    __syncthreads();
    for (int i = t; i < n; i += 256) atomicAdd(&hist[bk[i] >> 24], 1);
    __syncthreads();

    int v = hist[t];
    scn[t] = v;
    __syncthreads();
    for (int off = 1; off < 256; off <<= 1) {
        int add = (t >= off) ? scn[t - off] : 0;
        __syncthreads();
        scn[t] += add;
        __syncthreads();
    }
    int excl = scn[t] - v;
    int node = b * NPB + t;
    if (node < NN) row_ptr[node] = base + excl;

    hist[t] = excl;  // reuse as cursor
    __syncthreads();
    for (int i = t; i < n; i += 256) {
        unsigned pr = bk[i];
        int pos = atomicAdd(&hist[pr >> 24], 1);
        adj[base + pos] = (int)(pr & 0xFFFFFFu);
    }
}

// ---------------- prep: x -> bf16 AND all weights -> MFMA frag layout ----------------
// frag[(kt*(H/16)+nt)*64 + lane], elem i = W[kt*32 + (lane>>4)*8 + i][nt*16 + (lane&15)]

__device__ __forceinline__ void wfrag_one(const float* __restrict__ W, int H, int idx,
                                          uint4* __restrict__ out) {
    int lane = idx & 63;
    int tile = idx >> 6;
    int ntiles = H >> 4;
    int nt = tile % ntiles;
    int kt = tile / ntiles;
    int kbase = kt * 32 + (lane >> 4) * 8;
    int col = nt * 16 + (lane & 15);
    uint4 r;
    r.x = packbf(W[(size_t)(kbase + 0) * H + col], W[(size_t)(kbase + 1) * H + col]);
    r.y = packbf(W[(size_t)(kbase + 2) * H + col], W[(size_t)(kbase + 3) * H + col]);
    r.z = packbf(W[(size_t)(kbase + 4) * H + col], W[(size_t)(kbase + 5) * H + col]);
    r.w = packbf(W[(size_t)(kbase + 6) * H + col], W[(size_t)(kbase + 7) * H + col]);
    out[idx] = r;
}

__global__ __launch_bounds__(256) void prep_kernel(
    const float* __restrict__ x, unsigned int* __restrict__ x_bf,
    const float* __restrict__ W1l, const float* __restrict__ W1r,
    const float* __restrict__ W2l, const float* __restrict__ W2r,
    const float* __restrict__ W3l, const float* __restrict__ W3r,
    uint4* __restrict__ wf1, uint4* __restrict__ wf2,
    uint4* __restrict__ wf3l, uint4* __restrict__ wf3r) {
    int idx = blockIdx.x * blockDim.x + threadIdx.x;
    if (idx < CVT_N) {
        const float4* p = (const float4*)x + (size_t)idx * 2;
        float4 a = p[0], b = p[1];
        uint4 r;
        r.x = packbf(a.x, a.y);
        r.y = packbf(a.z, a.w);
        r.z = packbf(b.x, b.y);
        r.w = packbf(b.z, b.w);
        ((uint4*)x_bf)[idx] = r;
    } else {
        int k = idx - CVT_N;
        if (k < 2048)       wfrag_one(W1l, 128, k, wf1);
        else if (k < 4096)  wfrag_one(W1r, 128, k - 2048, wf1 + 2048);
        else if (k < 6144)  wfrag_one(W2l, 128, k - 4096, wf2);
        else if (k < 8192)  wfrag_one(W2r, 128, k - 6144, wf2 + 2048);
        else if (k < 9216)  wfrag_one(W3l, 64, k - 8192, wf3l);
        else if (k < 10240) wfrag_one(W3r, 64, k - 9216, wf3r);
    }
}

// ---------------- fused layer: pull_mean128 -> LDS -> MFMA GEMM -> relu -> bf16 out ----------------
// Block = 2 waves (128 thr), 32 nodes; wave w owns nodes [blk*32 + w*16, +16).
// 3125 blocks = 100000/32 exactly. Wave-local LDS tile, no barriers.

__global__ __launch_bounds__(128) void sage_fused_kernel(
    const uint4* __restrict__ xb4, const int* __restrict__ row_ptr,
    const int* __restrict__ adj, const uint4* __restrict__ wfrag,
    const float* __restrict__ bias, unsigned short* __restrict__ outb) {
    __shared__ uint4 As[32][17];  // +1 uint4 pad

    const int w = threadIdx.x >> 6;   // 0..1
    const int l = threadIdx.x & 63;
    const int g = l >> 4;   // edge-group 0..3
    const int i = l & 15;   // 16B chunk of row
    const int r0 = blockIdx.x * 32 + w * 16;

    // ---- phase 1: pull 16 node means ----
    for (int wnode = 0; wnode < 16; ++wnode) {
        int node = r0 + wnode;
        float acc[8];
#pragma unroll
        for (int j = 0; j < 8; ++j) acc[j] = 0.f;
        int beg = row_ptr[node];
        int end = row_ptr[node + 1];
        int p = beg;
        for (; p + 16 <= end; p += 16) {
#pragma unroll
            for (int j = 0; j < 4; ++j) {
                int s = adj[p + j * 4 + g];
                uint4 u = xb4[(size_t)s * 16 + i];
                acc[0] += bflo(u.x);
                acc[1] += bfhi(u.x);
                acc[2] += bflo(u.y);
                acc[3] += bfhi(u.y);
                acc[4] += bflo(u.z);
                acc[5] += bfhi(u.z);
                acc[6] += bflo(u.w);
                acc[7] += bfhi(u.w);
            }
        }
        if (p < end) {
#pragma unroll
            for (int j = 0; j < 4; ++j) {
                int e = p + j * 4 + g;
                bool vv = e < end;
                int s = vv ? adj[e] : 0;
                uint4 u = xb4[(size_t)s * 16 + i];
                float m = vv ? 1.f : 0.f;
                acc[0] = fmaf(m, bflo(u.x), acc[0]);
                acc[1] = fmaf(m, bfhi(u.x), acc[1]);
                acc[2] = fmaf(m, bflo(u.y), acc[2]);
                acc[3] = fmaf(m, bfhi(u.y), acc[3]);
                acc[4] = fmaf(m, bflo(u.z), acc[4]);
                acc[5] = fmaf(m, bfhi(u.z), acc[5]);
                acc[6] = fmaf(m, bflo(u.w), acc[6]);
                acc[7] = fmaf(m, bfhi(u.w), acc[7]);
            }
        }
#pragma unroll
        for (int j = 0; j < 8; ++j) {
            acc[j] += __shfl_xor(acc[j], 16);
            acc[j] += __shfl_xor(acc[j], 32);
        }
        if (g == 0) {
            float inv = 1.0f / (float)(end > beg ? (end - beg) : 1);
            uint4 r;
            r.x = packbf(acc[0] * inv, acc[1] * inv);
            r.y = packbf(acc[2] * inv, acc[3] * inv);
            r.z = packbf(acc[4] * inv, acc[5] * inv);
            r.w = packbf(acc[6] * inv, acc[7] * inv);
            As[w * 16 + wnode][i] = r;
        }
    }

    // ---- phase 2: GEMM (wave-local LDS agg + global xin) ----
    const int arow = r0 + (l & 15);

    f32x4 acc[8];
#pragma unroll
    for (int nt = 0; nt < 8; ++nt) {
        f32x4 z = {0.f, 0.f, 0.f, 0.f};
        acc[nt] = z;
    }

#pragma unroll
    for (int kt = 0; kt < 4; ++kt) {  // agg half from LDS
        bf16x8 av = as_bf8(As[w * 16 + (l & 15)][kt * 4 + g]);
#pragma unroll
        for (int nt = 0; nt < 8; ++nt) {
            bf16x8 bv = as_bf8(wfrag[(kt * 8 + nt) * 64 + l]);
            acc[nt] = __builtin_amdgcn_mfma_f32_16x16x32_bf16(av, bv, acc[nt], 0, 0, 0);
        }
    }
#pragma unroll
    for (int kt = 4; kt < 8; ++kt) {  // xin half from global
        bf16x8 av = as_bf8(xb4[(size_t)arow * 16 + (kt & 3) * 4 + g]);
#pragma unroll
        for (int nt = 0; nt < 8; ++nt) {
            bf16x8 bv = as_bf8(wfrag[(kt * 8 + nt) * 64 + l]);
            acc[nt] = __builtin_amdgcn_mfma_f32_16x16x32_bf16(av, bv, acc[nt], 0, 0, 0);
        }
    }

    const int crow0 = r0 + ((l >> 4) << 2);
    const int ccol = l & 15;
#pragma unroll
    for (int nt = 0; nt < 8; ++nt) {
        float bb = bias[nt * 16 + ccol];
#pragma unroll
        for (int q = 0; q < 4; ++q) {
            int r = crow0 + q;
            float v = fmaxf(acc[nt][q] + bb, 0.f);
            outb[(size_t)r * 128 + nt * 16 + ccol] = f2bf(v);
        }
    }
}

// ---------------- MFMA matmul z = h2 @ W3l (K=128 -> H=64), bf16 out ----------------

__global__ __launch_bounds__(256) void mm64_mfma_kernel(
    const uint4* __restrict__ A, const uint4* __restrict__ wfrag,
    unsigned short* __restrict__ outb) {
    const int w = threadIdx.x >> 6;
    const int l = threadIdx.x & 63;
    const int r0 = blockIdx.x * 64 + w * 16;
    int arow = r0 + (l & 15);
    if (arow > NN - 1) arow = NN - 1;
    const int koff = l >> 4;

    f32x4 acc[4];
#pragma unroll
    for (int nt = 0; nt < 4; ++nt) {
        f32x4 z = {0.f, 0.f, 0.f, 0.f};
        acc[nt] = z;
    }

#pragma unroll
    for (int kt = 0; kt < 4; ++kt) {
        bf16x8 av = as_bf8(A[(size_t)arow * 16 + kt * 4 + koff]);
#pragma unroll
        for (int nt = 0; nt < 4; ++nt) {
            bf16x8 bv = as_bf8(wfrag[(kt * 4 + nt) * 64 + l]);
            acc[nt] = __builtin_amdgcn_mfma_f32_16x16x32_bf16(av, bv, acc[nt], 0, 0, 0);
        }
    }

    const int crow0 = r0 + ((l >> 4) << 2);
    const int ccol = l & 15;
#pragma unroll
    for (int nt = 0; nt < 4; ++nt) {
        int col = nt * 16 + ccol;
#pragma unroll
        for (int q = 0; q < 4; ++q) {
            int r = crow0 + q;
            if (r < NN) outb[(size_t)r * 64 + col] = f2bf(acc[nt][q]);
        }
    }
}

// ---------------- fused final: pull_mean64(z) -> LDS, out = h2@W3r + agg + b3 (fp32) ----------------
// Block = 2 waves (128 thr), 32 nodes.

__global__ __launch_bounds__(128) void final_fused_kernel(
    const uint2* __restrict__ zb2, const int* __restrict__ row_ptr,
    const int* __restrict__ adj, const uint4* __restrict__ h2A,
    const uint4* __restrict__ wfrag, const float* __restrict__ bias,
    float* __restrict__ out) {
    __shared__ float As64[32][68];  // +4 f32 pad

    const int w = threadIdx.x >> 6;
    const int l = threadIdx.x & 63;
    const int g = l >> 4;
    const int i = l & 15;
    const int r0 = blockIdx.x * 32 + w * 16;

    // ---- phase 1: pull 16 node means of z (64-wide) ----
    for (int wnode = 0; wnode < 16; ++wnode) {
        int node = r0 + wnode;
        float acc[4];
#pragma unroll
        for (int j = 0; j < 4; ++j) acc[j] = 0.f;
        int beg = row_ptr[node];
        int end = row_ptr[node + 1];
        int p = beg;
        for (; p + 16 <= end; p += 16) {
#pragma unroll
            for (int j = 0; j < 4; ++j) {
                int s = adj[p + j * 4 + g];
                uint2 u = zb2[(size_t)s * 16 + i];
                acc[0] += bflo(u.x);
                acc[1] += bfhi(u.x);
                acc[2] += bflo(u.y);
                acc[3] += bfhi(u.y);
            }
        }
        if (p < end) {
#pragma unroll
            for (int j = 0; j < 4; ++j) {
                int e = p + j * 4 + g;
                bool vv = e < end;
                int s = vv ? adj[e] : 0;
                uint2 u = zb2[(size_t)s * 16 + i];
                float m = vv ? 1.f : 0.f;
                acc[0] = fmaf(m, bflo(u.x), acc[0]);
                acc[1] = fmaf(m, bfhi(u.x), acc[1]);
                acc[2] = fmaf(m, bflo(u.y), acc[2]);
                acc[3] = fmaf(m, bfhi(u.y), acc[3]);
            }
        }
#pragma unroll
        for (int j = 0; j < 4; ++j) {
            acc[j] += __shfl_xor(acc[j], 16);
            acc[j] += __shfl_xor(acc[j], 32);
        }
        if (g == 0) {
            float inv = 1.0f / (float)(end > beg ? (end - beg) : 1);
            float4 r;
            r.x = acc[0] * inv;
            r.y = acc[1] * inv;
            r.z = acc[2] * inv;
            r.w = acc[3] * inv;
            *(float4*)(&As64[w * 16 + wnode][i * 4]) = r;
        }
    }

    // ---- phase 2: out = h2 @ W3r + agg + bias ----
    const int arow = r0 + (l & 15);

    f32x4 acc[4];
#pragma unroll
    for (int nt = 0; nt < 4; ++nt) {
        f32x4 z = {0.f, 0.f, 0.f, 0.f};
        acc[nt] = z;
    }

#pragma unroll
    for (int kt = 0; kt < 4; ++kt) {
        bf16x8 av = as_bf8(h2A[(size_t)arow * 16 + kt * 4 + g]);
#pragma unroll
        for (int nt = 0; nt < 4; ++nt) {
            bf16x8 bv = as_bf8(wfrag[(kt * 4 + nt) * 64 + l]);
            acc[nt] = __builtin_amdgcn_mfma_f32_16x16x32_bf16(av, bv, acc[nt], 0, 0, 0);
        }
    }

    const int lrow0 = (l >> 4) << 2;
    const int ccol = l & 15;
#pragma unroll
    for (int nt = 0; nt < 4; ++nt) {
        int col = nt * 16 + ccol;
        float bb = bias[col];
#pragma unroll
        for (int q = 0; q < 4; ++q) {
            int r = r0 + lrow0 + q;
            float v = acc[nt][q] + As64[w * 16 + lrow0 + q][col] + bb;
            out[(size_t)r * 64 + col] = v;
        }
    }
}

// ---------------- launcher ----------------

extern "C" void kernel_launch(void* const* d_in, const int* in_sizes, int n_in,
                              void* d_out, int out_size, void* d_ws, size_t ws_size,
                              hipStream_t stream) {
    (void)in_sizes; (void)n_in; (void)out_size; (void)ws_size;

    const float* x   = (const float*)d_in[0];
    const int* eidx  = (const int*)d_in[1];
    const int* src   = eidx;
    const int* dst   = eidx + NE;
    const float* W1l = (const float*)d_in[2];
    const float* W1r = (const float*)d_in[3];
    const float* b1  = (const float*)d_in[4];
    const float* W2l = (const float*)d_in[5];
    const float* W2r = (const float*)d_in[6];
    const float* b2  = (const float*)d_in[7];
    const float* W3l = (const float*)d_in[8];
    const float* W3r = (const float*)d_in[9];
    const float* b3  = (const float*)d_in[10];
    float* out = (float*)d_out;

    size_t off = 0;
    auto carve = [&](size_t bytes) -> void* {
        void* p = (char*)d_ws + off;
        off += (bytes + 255) & ~(size_t)255;
        return p;
    };
    int* gcur    = (int*)carve((size_t)NB * 4);
    int* bstart  = (int*)carve((size_t)(NB + 1) * 4);
    int* row_ptr = (int*)carve((size_t)(NN + 1) * 4);
    int* adj     = (int*)carve((size_t)NE * 4);
    unsigned* buckets = (unsigned*)carve((size_t)NB * CAP * 4);         // 7.6 MB
    unsigned int* x_bf  = (unsigned int*)carve((size_t)NN * 64 * 4);    // N x 128 bf16
    unsigned int* h1_bf = (unsigned int*)carve((size_t)NN * 64 * 4);
    unsigned int* h2_bf = (unsigned int*)carve((size_t)NN * 64 * 4);
    unsigned int* z_bf  = (unsigned int*)carve((size_t)NN * 32 * 4);    // N x 64 bf16
    uint4* wf1  = (uint4*)carve((size_t)8 * 8 * 64 * 16);
    uint4* wf2  = (uint4*)carve((size_t)8 * 8 * 64 * 16);
    uint4* wf3l = (uint4*)carve((size_t)4 * 4 * 64 * 16);
    uint4* wf3r = (uint4*)carve((size_t)4 * 4 * 64 * 16);

    const int fgrid = NN / 32;                              // 3125 (exact)
    const int mgrid = (NN + 63) / 64;                       // 1563
    const int pgrid = (CVT_N + 10240 + 255) / 256;          // 6290

    // --- CSR build: scatter -> scan -> per-bucket finalize ---
    hipMemsetAsync(gcur, 0, (size_t)NB * 4, stream);
    bucket_scatter_kernel<<<NBLK_A, 256, 0, stream>>>(src, dst, gcur, buckets);
    bucket_scan_kernel<<<1, 512, 0, stream>>>(gcur, bstart, row_ptr);
    csr_finalize_kernel<<<NB, 256, 0, stream>>>(buckets, gcur, bstart, row_ptr, adj);

    // --- prep: x cvt + weight frags (one launch) ---
    prep_kernel<<<pgrid, 256, 0, stream>>>(x, x_bf, W1l, W1r, W2l, W2r, W3l, W3r,
                                           wf1, wf2, wf3l, wf3r);

    // --- layer 1 (fused pull + GEMM) ---
    sage_fused_kernel<<<fgrid, 128, 0, stream>>>((const uint4*)x_bf, row_ptr, adj,
                                                 wf1, b1, (unsigned short*)h1_bf);
    // --- layer 2 ---
    sage_fused_kernel<<<fgrid, 128, 0, stream>>>((const uint4*)h1_bf, row_ptr, adj,
                                                 wf2, b2, (unsigned short*)h2_bf);
    // --- layer 3 ---
    mm64_mfma_kernel<<<mgrid, 256, 0, stream>>>((const uint4*)h2_bf, wf3l,
                                                (unsigned short*)z_bf);
    final_fused_kernel<<<fgrid, 128, 0, stream>>>((const uint2*)z_bf, row_ptr, adj,
                                                  (const uint4*)h2_bf, wf3r, b3, out);
}